// Round 11
// baseline (239.843 us; speedup 1.0000x reference)
//
#include <hip/hip_runtime.h>
#include <math.h>

// Problem constants
#define B_  8
#define S_  384
#define H_  12
#define HD_ 64
#define E_  768
#define D_  768

typedef float  floatx4 __attribute__((ext_vector_type(4)));
typedef __bf16 bf16x8  __attribute__((ext_vector_type(8)));
typedef unsigned int ux4 __attribute__((ext_vector_type(4)));

__device__ __forceinline__ unsigned short f2bf(float f) {
    union { float f; unsigned u; } x; x.f = f;
    unsigned r = x.u + 0x7fff + ((x.u >> 16) & 1);
    return (unsigned short)(r >> 16);
}
__device__ __forceinline__ float bf2f(unsigned short u) {
    union { unsigned u; float f; } x; x.u = ((unsigned)u) << 16;
    return x.f;
}
__device__ __forceinline__ bf16x8 gld8(const unsigned short* p) {
    return __builtin_bit_cast(bf16x8, *(const ux4*)p);
}
// swizzled chunk address (shorts) for 128B-row tiles staged via global_load_lds
__device__ __forceinline__ int tadr(int row, int cD) {
    return (row * 8 + (cD ^ (row & 7))) * 8;
}
__device__ __forceinline__ bf16x8 lds8(const unsigned short* base, int row, int cD) {
    return __builtin_bit_cast(bf16x8, *(const ux4*)(base + tadr(row, cD)));
}

// ---------------------------------------------------------------------------
// Fused fp32 -> bf16 convert. grid=(576,11).
// ---------------------------------------------------------------------------
__global__ __launch_bounds__(256) void convert_all(
    const float* __restrict__ x,
    const float* __restrict__ Wq, const float* __restrict__ Wk,
    const float* __restrict__ Wv, const float* __restrict__ Wo,
    const float* __restrict__ Wpk, const float* __restrict__ Wpq,
    const float* __restrict__ rel128,
    unsigned short* __restrict__ xb,
    unsigned short* __restrict__ wqb, unsigned short* __restrict__ wkb,
    unsigned short* __restrict__ wvb, unsigned short* __restrict__ wob,
    unsigned short* __restrict__ wpkb, unsigned short* __restrict__ wpqb,
    unsigned short* __restrict__ relb)
{
    const int seg = blockIdx.y;
    const int e = (blockIdx.x * 256 + threadIdx.x) * 4;
    const float* src;
    unsigned short* dst;
    if (seg < 4)       { src = x + (size_t)seg * 589824; dst = xb + (size_t)seg * 589824; }
    else if (seg == 4) { src = Wq;  dst = wqb; }
    else if (seg == 5) { src = Wk;  dst = wkb; }
    else if (seg == 6) { src = Wv;  dst = wvb; }
    else if (seg == 7) { src = Wo;  dst = wob; }
    else if (seg == 8) { src = Wpk; dst = wpkb; }
    else if (seg == 9) { src = Wpq; dst = wpqb; }
    else               { src = rel128; dst = relb; }

    float4 v;
    if (seg == 10 && e >= 767 * 768) v = make_float4(0.f, 0.f, 0.f, 0.f);
    else                             v = *(const float4*)(src + e);
    ushort4 o;
    o.x = f2bf(v.x); o.y = f2bf(v.y); o.z = f2bf(v.z); o.w = f2bf(v.w);
    *(ushort4*)(dst + e) = o;
}

// ---------------------------------------------------------------------------
// Projection GEMMs (Q,K,Vt,pk,pq), 64x128 tile, BK=64, flat grid of 1008:
//   bid <  864 : z = bid/288 (Q,K,Vt), 48 m-tiles x 6 n-tiles
//   bid >= 864 : z = 3 + (bid-864)/72 (pk,pq), 12 m-tiles x 6 n-tiles
// ---------------------------------------------------------------------------
__global__ __launch_bounds__(256) void proj_all(
    const unsigned short* __restrict__ xb, const unsigned short* __restrict__ relb,
    const unsigned short* __restrict__ wq, const unsigned short* __restrict__ wk,
    const unsigned short* __restrict__ wv, const unsigned short* __restrict__ wpk,
    const unsigned short* __restrict__ wpq,
    const float* __restrict__ bq, const float* __restrict__ bk,
    const float* __restrict__ bv, const float* __restrict__ bpk,
    const float* __restrict__ bpq,
    unsigned short* __restrict__ qb, unsigned short* __restrict__ kb,
    unsigned short* __restrict__ vtb, unsigned short* __restrict__ pkb,
    unsigned short* __restrict__ pqb)
{
    const int bid = blockIdx.x;
    int z, mt, nt;
    if (bid < 864) {
        z = bid / 288; const int r = bid - z * 288; mt = r / 6; nt = r - mt * 6;
    } else {
        const int r2 = bid - 864; z = 3 + r2 / 72;
        const int r = r2 % 72; mt = r / 6; nt = r - mt * 6;
    }
    const int m0 = mt * 64, n0 = nt * 128;

    const unsigned short* A = (z < 3) ? xb : relb;
    const unsigned short* W = (z == 0) ? wq : (z == 1) ? wk : (z == 2) ? wv
                            : (z == 3) ? wpk : wpq;
    const float* bias = (z == 0) ? bq : (z == 1) ? bk : (z == 2) ? bv
                      : (z == 3) ? bpk : bpq;
    unsigned short* C = (z == 0) ? qb : (z == 1) ? kb : (z == 2) ? vtb
                      : (z == 3) ? pkb : pqb;

    __shared__ unsigned short As[64 * 64];     //  8 KB
    __shared__ unsigned short Ws[128 * 64];    // 16 KB

    const int tid  = threadIdx.x;
    const int lane = tid & 63;
    const int wv_  = tid >> 6;                 // N-strip of 32
    const int quad = lane >> 4, l16 = lane & 15;

    floatx4 acc[4][2];
#pragma unroll
    for (int i = 0; i < 4; ++i)
#pragma unroll
        for (int j = 0; j < 2; ++j) acc[i][j] = (floatx4){0.f, 0.f, 0.f, 0.f};

    for (int k0 = 0; k0 < 768; k0 += 64) {
        __syncthreads();
#pragma unroll
        for (int r = 0; r < 2; ++r) {
            const int idx = tid + 256 * r;     // 0..511: A 64 rows x 8 chunks
            const int row = idx >> 3, cL = idx & 7, cD = cL ^ (row & 7);
            __builtin_amdgcn_global_load_lds(
                (__attribute__((address_space(1))) void*)(A + (size_t)(m0 + row) * 768 + k0 + cD * 8),
                (__attribute__((address_space(3))) void*)&As[idx * 8], 16, 0, 0);
        }
#pragma unroll
        for (int r = 0; r < 4; ++r) {
            const int idx = tid + 256 * r;     // 0..1023: W 128 rows x 8 chunks
            const int row = idx >> 3, cL = idx & 7, cD = cL ^ (row & 7);
            __builtin_amdgcn_global_load_lds(
                (__attribute__((address_space(1))) void*)(W + (size_t)(n0 + row) * 768 + k0 + cD * 8),
                (__attribute__((address_space(3))) void*)&Ws[idx * 8], 16, 0, 0);
        }
        __syncthreads();

        bf16x8 a[4][2], b[2][2];
#pragma unroll
        for (int mi = 0; mi < 4; ++mi)
#pragma unroll
            for (int kc = 0; kc < 2; ++kc)
                a[mi][kc] = lds8(As, mi * 16 + l16, kc * 4 + quad);
#pragma unroll
        for (int ni = 0; ni < 2; ++ni)
#pragma unroll
            for (int kc = 0; kc < 2; ++kc)
                b[ni][kc] = lds8(Ws, wv_ * 32 + ni * 16 + l16, kc * 4 + quad);
#pragma unroll
        for (int mi = 0; mi < 4; ++mi)
#pragma unroll
            for (int ni = 0; ni < 2; ++ni)
#pragma unroll
                for (int kc = 0; kc < 2; ++kc)
                    acc[mi][ni] = __builtin_amdgcn_mfma_f32_16x16x32_bf16(
                        a[mi][kc], b[ni][kc], acc[mi][ni], 0, 0, 0);
    }

#pragma unroll
    for (int ni = 0; ni < 2; ++ni) {
        const int n = n0 + wv_ * 32 + ni * 16 + l16;
        const float bn = bias[n];
#pragma unroll
        for (int mi = 0; mi < 4; ++mi) {
            const int mbase = m0 + mi * 16 + quad * 4;
            if (z == 2) {
                const int bb = mbase / S_, s = mbase - bb * S_;
                const int h = n >> 6, hd = n & 63;
                ushort4 o;
                o.x = f2bf(acc[mi][ni][0] + bn);
                o.y = f2bf(acc[mi][ni][1] + bn);
                o.z = f2bf(acc[mi][ni][2] + bn);
                o.w = f2bf(acc[mi][ni][3] + bn);
                *(ushort4*)&C[(((size_t)(bb * H_ + h) << 6) + hd) * S_ + s] = o;
            } else if (z < 2) {
#pragma unroll
                for (int reg = 0; reg < 4; ++reg) {
                    const int m = mbase + reg;
                    const int bb = m / S_, s = m - bb * S_;
                    const int h = n >> 6, hd = n & 63;
                    C[(((size_t)(bb * H_ + h) * S_ + s) << 6) + hd] =
                        f2bf(acc[mi][ni][reg] + bn);
                }
            } else {
#pragma unroll
                for (int reg = 0; reg < 4; ++reg)
                    C[(size_t)(mbase + reg) * 768 + n] = f2bf(acc[mi][ni][reg] + bn);
            }
        }
    }
}

// ---------------------------------------------------------------------------
// Output projection: 64x128 tile, SPLIT-K x2 (kb = K half), grid = 576.
// Both halves atomicAdd fp32 into d_out (pre-zeroed); bias added by kb==0.
// ---------------------------------------------------------------------------
__global__ __launch_bounds__(256) void gemm_out(
    const unsigned short* __restrict__ A, const unsigned short* __restrict__ W,
    const float* __restrict__ bias, float* __restrict__ C)
{
    const int bid = blockIdx.x;
    const int kb = bid & 1;
    const int t  = bid >> 1;
    const int mt = t / 6, nt = t - mt * 6;
    const int m0 = mt * 64, n0 = nt * 128;

    __shared__ unsigned short As[64 * 64];
    __shared__ unsigned short Ws[128 * 64];

    const int tid  = threadIdx.x;
    const int lane = tid & 63;
    const int wv_  = tid >> 6;
    const int quad = lane >> 4, l16 = lane & 15;

    floatx4 acc[4][2];
#pragma unroll
    for (int i = 0; i < 4; ++i)
#pragma unroll
        for (int j = 0; j < 2; ++j) acc[i][j] = (floatx4){0.f, 0.f, 0.f, 0.f};

    const int kbeg = kb * 384, kend = kbeg + 384;
    for (int k0 = kbeg; k0 < kend; k0 += 64) {
        __syncthreads();
#pragma unroll
        for (int r = 0; r < 2; ++r) {
            const int idx = tid + 256 * r;
            const int row = idx >> 3, cL = idx & 7, cD = cL ^ (row & 7);
            __builtin_amdgcn_global_load_lds(
                (__attribute__((address_space(1))) void*)(A + (size_t)(m0 + row) * 768 + k0 + cD * 8),
                (__attribute__((address_space(3))) void*)&As[idx * 8], 16, 0, 0);
        }
#pragma unroll
        for (int r = 0; r < 4; ++r) {
            const int idx = tid + 256 * r;
            const int row = idx >> 3, cL = idx & 7, cD = cL ^ (row & 7);
            __builtin_amdgcn_global_load_lds(
                (__attribute__((address_space(1))) void*)(W + (size_t)(n0 + row) * 768 + k0 + cD * 8),
                (__attribute__((address_space(3))) void*)&Ws[idx * 8], 16, 0, 0);
        }
        __syncthreads();

        bf16x8 a[4][2], b[2][2];
#pragma unroll
        for (int mi = 0; mi < 4; ++mi)
#pragma unroll
            for (int kc = 0; kc < 2; ++kc)
                a[mi][kc] = lds8(As, mi * 16 + l16, kc * 4 + quad);
#pragma unroll
        for (int ni = 0; ni < 2; ++ni)
#pragma unroll
            for (int kc = 0; kc < 2; ++kc)
                b[ni][kc] = lds8(Ws, wv_ * 32 + ni * 16 + l16, kc * 4 + quad);
#pragma unroll
        for (int mi = 0; mi < 4; ++mi)
#pragma unroll
            for (int ni = 0; ni < 2; ++ni)
#pragma unroll
                for (int kc = 0; kc < 2; ++kc)
                    acc[mi][ni] = __builtin_amdgcn_mfma_f32_16x16x32_bf16(
                        a[mi][kc], b[ni][kc], acc[mi][ni], 0, 0, 0);
    }

#pragma unroll
    for (int ni = 0; ni < 2; ++ni) {
        const int n = n0 + wv_ * 32 + ni * 16 + l16;
        const float bn = (kb == 0) ? bias[n] : 0.f;
#pragma unroll
        for (int mi = 0; mi < 4; ++mi)
#pragma unroll
            for (int reg = 0; reg < 4; ++reg) {
                const int m = m0 + mi * 16 + quad * 4 + reg;
                atomicAdd(&C[(size_t)m * 768 + n], acc[mi][ni][reg] + bn);
            }
    }
}

// ---------------------------------------------------------------------------
// MFMA flash attention, R20 (resubmitted after infra failure): split-j 6->2.
// Each block sweeps 3 consecutive j-tiles (jt = 3*jh + t) with a CIRCULAR
// 128-row PK/PQ window: consecutive tiles' windows overlap by 64 rows (dbase
// shifts -64/tile), so staging is 128 + 2x64 = 256 rows instead of 3x128
// (-33% DMA -- R15's proven lever). Q + i-metadata amortized x3; partial-O
// traffic /3; merge /3. Softmax is ONLINE in the register layout: per-lane
// scalar (m_run,l_run); O-rescale factors fetched by 4 __shfl. Physical LDS
// row = global_row & 127 (swizzle invariant: p&7 == grow&7). Barriers: 1
// initial + per transition {read-protect, staging-done}, each covered. 5 total.
// LDS = PKs 16K + PQs 16K + CP 17K = 49 KB -> 3 blocks/CU.
// grid = (6 it, 12 h, 16 = b*2+jh); 256 thr = 4 waves.
// R16/R18 lessons kept: K/Vt/Q stay direct (same-panel locality only).
// ---------------------------------------------------------------------------
__global__ __launch_bounds__(256, 3) void attn_mfma(
    const unsigned short* __restrict__ qg, const unsigned short* __restrict__ kg,
    const unsigned short* __restrict__ vtg,
    const unsigned short* __restrict__ pkg, const unsigned short* __restrict__ pqg,
    const int* __restrict__ seg, const float* __restrict__ sep,
    const int* __restrict__ mask,
    const float* __restrict__ same_bias, const float* __restrict__ cross_bias,
    const float* __restrict__ sep_scale, const float* __restrict__ sep_decay,
    unsigned short* __restrict__ part_O, float* __restrict__ part_ml)
{
    __shared__ unsigned short PKs[128 * 64];   // 16 KB circular window
    __shared__ unsigned short PQs[128 * 64];   // 16 KB
    __shared__ float CP[64 * 68];              // 17 KB score tile (wave-private rows)

    const int tid  = threadIdx.x;
    const int lane = tid & 63, w = tid >> 6;
    const int l16  = lane & 15, quad = lane >> 4;
    const int it = blockIdx.x, h = blockIdx.y;
    const int b  = blockIdx.z >> 1, jh = blockIdx.z & 1;
    const int i0 = it * 64;
    const size_t bh = (size_t)(b * H_ + h);

    const unsigned short* kbase  = kg  + bh * S_ * 64;
    const unsigned short* vtbase = vtg + bh * 64 * S_;
    const int db0 = i0 - jh * 192 + 320;       // dbase for t=0 (window [db0,db0+128))

    // ---- initial staging: full 128-row window for tile 0 ----
#pragma unroll
    for (int r = 0; r < 4; ++r) {
        const int idx = tid + 256 * r;         // 0..1023
        const int grow = db0 + (idx >> 3);     // global pk/pq row
        const int p = grow & 127;              // circular physical row
        const int cL = idx & 7, cD = cL ^ (grow & 7);
        const size_t go = (size_t)grow * 768 + h * 64 + cD * 8;
        __builtin_amdgcn_global_load_lds(
            (__attribute__((address_space(1))) void*)(pkg + go),
            (__attribute__((address_space(3))) void*)&PKs[(p * 8 + cL) * 8], 16, 0, 0);
        __builtin_amdgcn_global_load_lds(
            (__attribute__((address_space(1))) void*)(pqg + go),
            (__attribute__((address_space(3))) void*)&PQs[(p * 8 + cL) * 8], 16, 0, 0);
    }

    // ---- per-block invariants (fly during staging) ----
    const int row = 16 * w + l16;              // softmax row this lane owns
    bf16x8 qf[2];
#pragma unroll
    for (int ks = 0; ks < 2; ++ks)
        qf[ks] = gld8(qg + (bh * S_ + i0 + 16 * w + l16) * 64 + ks * 32 + quad * 8);
    const float aii = fabsf(sep[b * S_ + i0 + row]);
    const int   sii = seg[b * S_ + i0 + row];

    const float sb  = same_bias[h];
    const float cb  = cross_bias[h];
    const float ssc = sep_scale[h];
    const float sd  = sep_decay[h];
    const float dec = fmaxf(sd, 0.f) + log1pf(__expf(-fabsf(sd))) + 1e-4f;
    const float isc = 0.07216878364870323f;    // 1/sqrt(64*3)

    // ---- tile-0 operands (direct, in flight with staging) ----
    bf16x8 kf[4][2], vtf[4][2];
    float ajv[16]; int sjv[16], mkv[16];
    {
        const int j0 = jh * 192;
#pragma unroll
        for (int nj = 0; nj < 4; ++nj)
#pragma unroll
            for (int ks = 0; ks < 2; ++ks)
                kf[nj][ks] = gld8(kbase + (size_t)(j0 + 16 * nj + l16) * 64
                                  + ks * 32 + quad * 8);
#pragma unroll
        for (int nd = 0; nd < 4; ++nd)
#pragma unroll
            for (int ks = 0; ks < 2; ++ks)
                vtf[nd][ks] = gld8(vtbase + (size_t)(16 * nd + l16) * S_
                                   + j0 + ks * 32 + quad * 8);
        const float* sepj = sep  + b * S_ + j0;
        const int*   segj = seg  + b * S_ + j0;
        const int*   mskj = mask + b * S_ + j0;
        *(float4*)&ajv[0]  = *(const float4*)&sepj[quad * 8];
        *(float4*)&ajv[4]  = *(const float4*)&sepj[quad * 8 + 4];
        *(float4*)&ajv[8]  = *(const float4*)&sepj[32 + quad * 8];
        *(float4*)&ajv[12] = *(const float4*)&sepj[32 + quad * 8 + 4];
        *(int4*)&sjv[0]  = *(const int4*)&segj[quad * 8];
        *(int4*)&sjv[4]  = *(const int4*)&segj[quad * 8 + 4];
        *(int4*)&sjv[8]  = *(const int4*)&segj[32 + quad * 8];
        *(int4*)&sjv[12] = *(const int4*)&segj[32 + quad * 8 + 4];
        *(int4*)&mkv[0]  = *(const int4*)&mskj[quad * 8];
        *(int4*)&mkv[4]  = *(const int4*)&mskj[quad * 8 + 4];
        *(int4*)&mkv[8]  = *(const int4*)&mskj[32 + quad * 8];
        *(int4*)&mkv[12] = *(const int4*)&mskj[32 + quad * 8 + 4];
    }
    float biasv[16]; unsigned mkbits = 0;
#pragma unroll
    for (int e = 0; e < 16; ++e) {
        const float gap = fabsf(aii - fabsf(ajv[e]));
        biasv[e] = (sii == sjv[e]) ? sb : cb + __expf(-gap * dec) * ssc;
        mkbits |= (mkv[e] != 0 ? 1u : 0u) << e;
    }

    // online-softmax state + output accumulator
    float m_run = -INFINITY, l_run = 0.f;
    floatx4 O[4];
#pragma unroll
    for (int nd = 0; nd < 4; ++nd) O[nd] = (floatx4){0.f, 0.f, 0.f, 0.f};

    // ---- c2c(0): pre-barrier, covers initial staging ----
#pragma unroll
    for (int nj = 0; nj < 4; ++nj) {
        floatx4 acc = (floatx4){0.f, 0.f, 0.f, 0.f};
#pragma unroll
        for (int ks = 0; ks < 2; ++ks)
            acc = __builtin_amdgcn_mfma_f32_16x16x32_bf16(qf[ks], kf[nj][ks], acc, 0, 0, 0);
#pragma unroll
        for (int reg = 0; reg < 4; ++reg) {
            const int ii = 16 * w + quad * 4 + reg;
            CP[ii * 68 + 16 * nj + l16] = acc[reg];
        }
    }

    __syncthreads();   // staging(0) complete

#pragma unroll
    for (int t = 0; t < 3; ++t) {
        const int dbt = db0 - 64 * t;          // window base for tile t

        // ---- c2p(t): PKs window + qf; scatter jj = ii - ddloc + 63 ----
#pragma unroll
        for (int f = 0; f < 5; ++f) {
            const int nd = w + f;
            floatx4 acc = (floatx4){0.f, 0.f, 0.f, 0.f};
#pragma unroll
            for (int ks = 0; ks < 2; ++ks) {
                bf16x8 bf = lds8(PKs, (dbt + 16 * nd + l16) & 127, ks * 4 + quad);
                acc = __builtin_amdgcn_mfma_f32_16x16x32_bf16(qf[ks], bf, acc, 0, 0, 0);
            }
            const int ddloc = 16 * nd + l16;
#pragma unroll
            for (int reg = 0; reg < 4; ++reg) {
                const int ii = 16 * w + quad * 4 + reg;
                const int jj = ii - ddloc + 63;
                if (jj >= 0 && jj < 64)
                    CP[ii * 68 + jj] += acc[reg];      // unique writer per cell
            }
        }

        // ---- p2c(t): A=PQ window, B=kf ----
#pragma unroll
        for (int f = 0; f < 5; ++f) {
            const int nd = w + f;
            bf16x8 pqf[2];
#pragma unroll
            for (int ks = 0; ks < 2; ++ks)
                pqf[ks] = lds8(PQs, (dbt + 16 * nd + l16) & 127, ks * 4 + quad);
#pragma unroll
            for (int g = 0; g < 2; ++g) {
                const int nj = (g == 0) ? (3 - f) : (4 - f);
                if (nj < 0 || nj > 3) continue;
                floatx4 acc = (floatx4){0.f, 0.f, 0.f, 0.f};
#pragma unroll
                for (int ks = 0; ks < 2; ++ks)
                    acc = __builtin_amdgcn_mfma_f32_16x16x32_bf16(pqf[ks], kf[nj][ks], acc, 0, 0, 0);
                const int jj = 16 * nj + l16;
#pragma unroll
                for (int reg = 0; reg < 4; ++reg) {
                    const int ddloc = 16 * nd + quad * 4 + reg;
                    const int ii = ddloc + jj - 63;
                    if (ii >= 16 * w && ii < 16 * w + 16)
                        CP[ii * 68 + jj] += acc[reg];  // unique writer per cell
                }
            }
        }

        // ---- online register softmax for tile t ----
        floatx4 cp0 = *(const floatx4*)&CP[row * 68 + quad * 8];
        floatx4 cp1 = *(const floatx4*)&CP[row * 68 + quad * 8 + 4];
        floatx4 cp2 = *(const floatx4*)&CP[row * 68 + 32 + quad * 8];
        floatx4 cp3 = *(const floatx4*)&CP[row * 68 + 32 + quad * 8 + 4];

        float lg[16];
        float tmax = -INFINITY;
#pragma unroll
        for (int e = 0; e < 16; ++e) {
            const float cpv = (e < 4) ? cp0[e] : (e < 8) ? cp1[e - 4]
                            : (e < 12) ? cp2[e - 8] : cp3[e - 12];
            float xv = cpv * isc + biasv[e];
            if (!((mkbits >> e) & 1u)) xv = -9.0e15f;
            lg[e] = xv;
            tmax = fmaxf(tmax, xv);
        }
        tmax = fmaxf(tmax, __shfl_xor(tmax, 16));
        tmax = fmaxf(tmax, __shfl_xor(tmax, 32));

        const float newm  = fmaxf(m_run, tmax);
        const float scale = __expf(m_run - newm);
        m_run = newm;

        float rs = 0.f;
        unsigned int pk32[8];
#pragma unroll
        for (int e = 0; e < 8; ++e) {
            const float e0 = __expf(lg[2 * e]     - newm);
            const float e1 = __expf(lg[2 * e + 1] - newm);
            rs += e0 + e1;
            pk32[e] = (unsigned)f2bf(e0) | ((unsigned)f2bf(e1) << 16);
        }
        rs += __shfl_xor(rs, 16);
        rs += __shfl_xor(rs, 32);
        l_run = l_run * scale + rs;

        // ---- transition part 1: protect window t, start staging t+1 ----
        if (t < 2) {
            __syncthreads();                   // all waves done reading window t
            const int dbn = dbt - 64;          // new rows [dbn, dbn+64)
#pragma unroll
            for (int r = 0; r < 2; ++r) {
                const int idx = tid + 256 * r; // 0..511
                const int grow = dbn + (idx >> 3);
                const int p = grow & 127;
                const int cL = idx & 7, cD = cL ^ (grow & 7);
                const size_t go = (size_t)grow * 768 + h * 64 + cD * 8;
                __builtin_amdgcn_global_load_lds(
                    (__attribute__((address_space(1))) void*)(pkg + go),
                    (__attribute__((address_space(3))) void*)&PKs[(p * 8 + cL) * 8], 16, 0, 0);
                __builtin_amdgcn_global_load_lds(
                    (__attribute__((address_space(1))) void*)(pqg + go),
                    (__attribute__((address_space(3))) void*)&PQs[(p * 8 + cL) * 8], 16, 0, 0);
            }
            // next tile's K + j-metadata (kf free after p2c(t); c2c(t+1) uses new kf)
            const int j0n = jh * 192 + (t + 1) * 64;
#pragma unroll
            for (int nj = 0; nj < 4; ++nj)
#pragma unroll
                for (int ks = 0; ks < 2; ++ks)
                    kf[nj][ks] = gld8(kbase + (size_t)(j0n + 16 * nj + l16) * 64
                                      + ks * 32 + quad * 8);
            const float* sepj = sep  + b * S_ + j0n;
            const int*   segj = seg  + b * S_ + j0n;
            const int*   mskj = mask + b * S_ + j0n;
            *(float4*)&ajv[0]  = *(const float4*)&sepj[quad * 8];
            *(float4*)&ajv[4]  = *(const float4*)&sepj[quad * 8 + 4];
            *(float4*)&ajv[8]  = *(const float4*)&sepj[32 + quad * 8];
            *(float4*)&ajv[12] = *(const float4*)&sepj[32 + quad * 8 + 4];
            *(int4*)&sjv[0]  = *(const int4*)&segj[quad * 8];
            *(int4*)&sjv[4]  = *(const int4*)&segj[quad * 8 + 4];
            *(int4*)&sjv[8]  = *(const int4*)&segj[32 + quad * 8];
            *(int4*)&sjv[12] = *(const int4*)&segj[32 + quad * 8 + 4];
            *(int4*)&mkv[0]  = *(const int4*)&mskj[quad * 8];
            *(int4*)&mkv[4]  = *(const int4*)&mskj[quad * 8 + 4];
            *(int4*)&mkv[8]  = *(const int4*)&mskj[32 + quad * 8];
            *(int4*)&mkv[12] = *(const int4*)&mskj[32 + quad * 8 + 4];
        }

        // ---- rescale O (per-row scale via 4 shuffles) + PV(t) ----
        float sc_r[4];
#pragma unroll
        for (int reg = 0; reg < 4; ++reg)
            sc_r[reg] = __shfl(scale, (lane & 48) | (quad * 4 + reg));
        bf16x8 pA[2];
        pA[0] = __builtin_bit_cast(bf16x8, (ux4){pk32[0], pk32[1], pk32[2], pk32[3]});
        pA[1] = __builtin_bit_cast(bf16x8, (ux4){pk32[4], pk32[5], pk32[6], pk32[7]});
#pragma unroll
        for (int nd = 0; nd < 4; ++nd) {
#pragma unroll
            for (int reg = 0; reg < 4; ++reg)
                O[nd][reg] *= sc_r[reg];
#pragma unroll
            for (int ks = 0; ks < 2; ++ks)
                O[nd] = __builtin_amdgcn_mfma_f32_16x16x32_bf16(pA[ks], vtf[nd][ks], O[nd], 0, 0, 0);
        }

        // ---- transition part 2: Vt(t+1), bias(t+1), c2c(t+1), barrier ----
        if (t < 2) {
            const int j0n = jh * 192 + (t + 1) * 64;
#pragma unroll
            for (int nd = 0; nd < 4; ++nd)
#pragma unroll
                for (int ks = 0; ks < 2; ++ks)
                    vtf[nd][ks] = gld8(vtbase + (size_t)(16 * nd + l16) * S_
                                       + j0n + ks * 32 + quad * 8);
            mkbits = 0;
#pragma unroll
            for (int e = 0; e < 16; ++e) {
                const float gap = fabsf(aii - fabsf(ajv[e]));
                biasv[e] = (sii == sjv[e]) ? sb : cb + __expf(-gap * dec) * ssc;
                mkbits |= (mkv[e] != 0 ? 1u : 0u) << e;
            }
            // c2c(t+1): CP rows wave-private; covers incremental staging
#pragma unroll
            for (int nj = 0; nj < 4; ++nj) {
                floatx4 acc = (floatx4){0.f, 0.f, 0.f, 0.f};
#pragma unroll
                for (int ks = 0; ks < 2; ++ks)
                    acc = __builtin_amdgcn_mfma_f32_16x16x32_bf16(qf[ks], kf[nj][ks], acc, 0, 0, 0);
#pragma unroll
                for (int reg = 0; reg < 4; ++reg) {
                    const int ii = 16 * w + quad * 4 + reg;
                    CP[ii * 68 + 16 * nj + l16] = acc[reg];
                }
            }
            __syncthreads();                   // staging(t+1) complete
        }
    }

    // ---- epilogue: write unnormalized partial O + (m,l) for this jh half ----
    const int idx = (int)((b * H_ + h) * 6 + it);
    unsigned short* pO = part_O + (size_t)(jh * 576 + idx) * 4096;
#pragma unroll
    for (int nd = 0; nd < 4; ++nd) {
        const int d = 16 * nd + l16;
#pragma unroll
        for (int reg = 0; reg < 4; ++reg) {
            const int ii = 16 * w + quad * 4 + reg;
            pO[ii * 64 + d] = f2bf(O[nd][reg]);
        }
    }
    float* pml = part_ml + (size_t)(jh * 576 + idx) * 128;
    if (quad == 0) {
        pml[row]      = m_run;
        pml[64 + row] = l_run;
    }
}

// ---------------------------------------------------------------------------
// Merge the 2 split-j partials -> vals (bf16, (B,S,E)). grid=576, 256 thr.
// ---------------------------------------------------------------------------
__global__ __launch_bounds__(256) void merge_attn(
    const unsigned short* __restrict__ part_O, const float* __restrict__ part_ml,
    unsigned short* __restrict__ vals)
{
    const int idx = blockIdx.x;                 // ((b*H+h)*6+it)
    const int b  = idx / (H_ * 6);
    const int r  = idx - b * H_ * 6;
    const int h  = r / 6, it = r - h * 6;
    const int tid = threadIdx.x;
    const int ii = tid >> 2, c = (tid & 3) * 16;

    float m[2], l[2];
#pragma unroll
    for (int jc = 0; jc < 2; ++jc) {
        const float* pml = part_ml + (size_t)(jc * 576 + idx) * 128;
        m[jc] = pml[ii];
        l[jc] = pml[64 + ii];
    }
    float M = fmaxf(m[0], m[1]);
    float wsum = 0.f, wc[2];
#pragma unroll
    for (int jc = 0; jc < 2; ++jc) {
        wc[jc] = __expf(m[jc] - M);
        wsum += wc[jc] * l[jc];
    }
    const float inv = (wsum > 0.f) ? 1.f / wsum : 0.f;

    float o[16];
#pragma unroll
    for (int e = 0; e < 16; ++e) o[e] = 0.f;
#pragma unroll
    for (int jc = 0; jc < 2; ++jc) {
        const unsigned short* pO = part_O + ((size_t)(jc * 576 + idx)) * 4096
                                 + ii * 64 + c;
        ux4 u0 = *(const ux4*)pO;
        ux4 u1 = *(const ux4*)(pO + 8);
        const unsigned short* us0 = (const unsigned short*)&u0;
        const unsigned short* us1 = (const unsigned short*)&u1;
#pragma unroll
        for (int e = 0; e < 8; ++e) {
            o[e]     += wc[jc] * bf2f(us0[e]);
            o[8 + e] += wc[jc] * bf2f(us1[e]);
        }
    }
    ushort4 w0, w1, w2, w3;
#pragma unroll
    for (int e = 0; e < 4; ++e) {
        ((unsigned short*)&w0)[e] = f2bf(o[e] * inv);
        ((unsigned short*)&w1)[e] = f2bf(o[4 + e] * inv);
        ((unsigned short*)&w2)[e] = f2bf(o[8 + e] * inv);
        ((unsigned short*)&w3)[e] = f2bf(o[12 + e] * inv);
    }
    unsigned short* dst = vals + ((size_t)(b * S_ + it * 64 + ii)) * E_ + h * 64 + c;
    *(ushort4*)(dst)      = w0;
    *(ushort4*)(dst + 4)  = w1;
    *(ushort4*)(dst + 8)  = w2;
    *(ushort4*)(dst + 12) = w3;
}

// ---------------------------------------------------------------------------
// Launcher. Workspace (shorts unless noted): xb 2359296; 7x589824 weights/rel;
// qb,kb,vtb 3x2359296; pkb,pqb 2x589824; valsb 2359296; part_O 2x576x4096;
// part_ml fp32 2x576x128. ~60 MiB.
// ---------------------------------------------------------------------------
extern "C" void kernel_launch(void* const* d_in, const int* in_sizes, int n_in,
                              void* d_out, int out_size, void* d_ws, size_t ws_size,
                              hipStream_t stream)
{
    const float* x         = (const float*)d_in[0];
    const int*   mask      = (const int*)d_in[1];
    const int*   seg       = (const int*)d_in[2];
    const float* sep       = (const float*)d_in[3];
    const float* Wq        = (const float*)d_in[4];
    const float* bq        = (const float*)d_in[5];
    const float* Wk        = (const float*)d_in[6];
    const float* bk        = (const float*)d_in[7];
    const float* Wv        = (const float*)d_in[8];
    const float* bv        = (const float*)d_in[9];
    const float* rel_emb   = (const float*)d_in[10];
    const float* Wpk       = (const float*)d_in[11];
    const float* bpk       = (const float*)d_in[12];
    const float* Wpq       = (const float*)d_in[13];
    const float* bpq       = (const float*)d_in[14];
    const float* same_bias = (const float*)d_in[15];
    const float* cross_bias= (const float*)d_in[16];
    const float* sep_scale = (const float*)d_in[17];
    const float* sep_decay = (const float*)d_in[18];
    const float* Wo        = (const float*)d_in[19];
    const float* bo        = (const float*)d_in[20];

    const size_t QKVN = (size_t)B_ * S_ * E_;   // 2359296
    const size_t WN   = (size_t)768 * 768;      //  589824

    unsigned short* xb    = (unsigned short*)d_ws;
    unsigned short* wqb   = xb   + QKVN;
    unsigned short* wkb   = wqb  + WN;
    unsigned short* wvb   = wkb  + WN;
    unsigned short* wob   = wvb  + WN;
    unsigned short* wpkb  = wob  + WN;
    unsigned short* wpqb  = wpkb + WN;
    unsigned short* relb  = wpqb + WN;
    unsigned short* qb    = relb + WN;
    unsigned short* kb    = qb   + QKVN;
    unsigned short* vtb   = kb   + QKVN;
    unsigned short* pkb   = vtb  + QKVN;
    unsigned short* pqb   = pkb  + WN;
    unsigned short* valsb = pqb  + WN;
    unsigned short* partO = valsb + QKVN;                       // 2*576*4096 shorts
    float*          partml= (float*)(partO + (size_t)2 * 576 * 4096);

    // 0) pre-zero d_out for gemm_out's split-K atomic accumulation
    hipMemsetAsync(d_out, 0, (size_t)out_size, stream);

    // 1) convert all operands to bf16
    convert_all<<<dim3(576, 11), 256, 0, stream>>>(
        x, Wq, Wk, Wv, Wo, Wpk, Wpq, rel_emb + (size_t)128 * D_,
        xb, wqb, wkb, wvb, wob, wpkb, wpqb, relb);

    // 2) fused Q/K/Vt/pk/pq projections (64x128 tiles, 1008 blocks)
    proj_all<<<dim3(1008), 256, 0, stream>>>(
        xb, relb, wqb, wkb, wvb, wpkb, wpqb,
        bq, bk, bv, bpk, bpq, qb, kb, vtb, pkb, pqb);

    // 3) MFMA flash attention (R20: circular-window j-sweep), split-j x2
    attn_mfma<<<dim3(6, 12, 16), 256, 0, stream>>>(
        qb, kb, vtb, pkb, pqb, seg, sep, mask,
        same_bias, cross_bias, sep_scale, sep_decay, partO, partml);

    // 4) merge 2 partials -> valsb
    merge_attn<<<dim3(576), 256, 0, stream>>>(partO, partml, valsb);

    // 5) output projection (64x128 tiles, SPLIT-K x2, 576 blocks, atomic)
    gemm_out<<<dim3(576), 256, 0, stream>>>(valsb, wob, bo, (float*)d_out);
}

// Round 12
// 211.663 us; speedup vs baseline: 1.1331x; 1.1331x over previous
//
#include <hip/hip_runtime.h>
#include <math.h>

// Problem constants
#define B_  8
#define S_  384
#define H_  12
#define HD_ 64
#define E_  768
#define D_  768

typedef float  floatx4 __attribute__((ext_vector_type(4)));
typedef __bf16 bf16x8  __attribute__((ext_vector_type(8)));
typedef unsigned int ux4 __attribute__((ext_vector_type(4)));

__device__ __forceinline__ unsigned short f2bf(float f) {
    union { float f; unsigned u; } x; x.f = f;
    unsigned r = x.u + 0x7fff + ((x.u >> 16) & 1);
    return (unsigned short)(r >> 16);
}
__device__ __forceinline__ float bf2f(unsigned short u) {
    union { unsigned u; float f; } x; x.u = ((unsigned)u) << 16;
    return x.f;
}
__device__ __forceinline__ bf16x8 gld8(const unsigned short* p) {
    return __builtin_bit_cast(bf16x8, *(const ux4*)p);
}
// swizzled chunk address (shorts) for 128B-row tiles staged via global_load_lds
__device__ __forceinline__ int tadr(int row, int cD) {
    return (row * 8 + (cD ^ (row & 7))) * 8;
}
__device__ __forceinline__ bf16x8 lds8(const unsigned short* base, int row, int cD) {
    return __builtin_bit_cast(bf16x8, *(const ux4*)(base + tadr(row, cD)));
}

// ---------------------------------------------------------------------------
// Fused fp32 -> bf16 convert. grid=(576,11).
// ---------------------------------------------------------------------------
__global__ __launch_bounds__(256) void convert_all(
    const float* __restrict__ x,
    const float* __restrict__ Wq, const float* __restrict__ Wk,
    const float* __restrict__ Wv, const float* __restrict__ Wo,
    const float* __restrict__ Wpk, const float* __restrict__ Wpq,
    const float* __restrict__ rel128,
    unsigned short* __restrict__ xb,
    unsigned short* __restrict__ wqb, unsigned short* __restrict__ wkb,
    unsigned short* __restrict__ wvb, unsigned short* __restrict__ wob,
    unsigned short* __restrict__ wpkb, unsigned short* __restrict__ wpqb,
    unsigned short* __restrict__ relb)
{
    const int seg = blockIdx.y;
    const int e = (blockIdx.x * 256 + threadIdx.x) * 4;
    const float* src;
    unsigned short* dst;
    if (seg < 4)       { src = x + (size_t)seg * 589824; dst = xb + (size_t)seg * 589824; }
    else if (seg == 4) { src = Wq;  dst = wqb; }
    else if (seg == 5) { src = Wk;  dst = wkb; }
    else if (seg == 6) { src = Wv;  dst = wvb; }
    else if (seg == 7) { src = Wo;  dst = wob; }
    else if (seg == 8) { src = Wpk; dst = wpkb; }
    else if (seg == 9) { src = Wpq; dst = wpqb; }
    else               { src = rel128; dst = relb; }

    float4 v;
    if (seg == 10 && e >= 767 * 768) v = make_float4(0.f, 0.f, 0.f, 0.f);
    else                             v = *(const float4*)(src + e);
    ushort4 o;
    o.x = f2bf(v.x); o.y = f2bf(v.y); o.z = f2bf(v.z); o.w = f2bf(v.w);
    *(ushort4*)(dst + e) = o;
}

// ---------------------------------------------------------------------------
// Projection GEMMs (Q,K,Vt,pk,pq), 64x128 tile, BK=64, flat grid of 1008:
//   bid <  864 : z = bid/288 (Q,K,Vt), 48 m-tiles x 6 n-tiles
//   bid >= 864 : z = 3 + (bid-864)/72 (pk,pq), 12 m-tiles x 6 n-tiles
// ---------------------------------------------------------------------------
__global__ __launch_bounds__(256) void proj_all(
    const unsigned short* __restrict__ xb, const unsigned short* __restrict__ relb,
    const unsigned short* __restrict__ wq, const unsigned short* __restrict__ wk,
    const unsigned short* __restrict__ wv, const unsigned short* __restrict__ wpk,
    const unsigned short* __restrict__ wpq,
    const float* __restrict__ bq, const float* __restrict__ bk,
    const float* __restrict__ bv, const float* __restrict__ bpk,
    const float* __restrict__ bpq,
    unsigned short* __restrict__ qb, unsigned short* __restrict__ kb,
    unsigned short* __restrict__ vtb, unsigned short* __restrict__ pkb,
    unsigned short* __restrict__ pqb)
{
    const int bid = blockIdx.x;
    int z, mt, nt;
    if (bid < 864) {
        z = bid / 288; const int r = bid - z * 288; mt = r / 6; nt = r - mt * 6;
    } else {
        const int r2 = bid - 864; z = 3 + r2 / 72;
        const int r = r2 % 72; mt = r / 6; nt = r - mt * 6;
    }
    const int m0 = mt * 64, n0 = nt * 128;

    const unsigned short* A = (z < 3) ? xb : relb;
    const unsigned short* W = (z == 0) ? wq : (z == 1) ? wk : (z == 2) ? wv
                            : (z == 3) ? wpk : wpq;
    const float* bias = (z == 0) ? bq : (z == 1) ? bk : (z == 2) ? bv
                      : (z == 3) ? bpk : bpq;
    unsigned short* C = (z == 0) ? qb : (z == 1) ? kb : (z == 2) ? vtb
                      : (z == 3) ? pkb : pqb;

    __shared__ unsigned short As[64 * 64];     //  8 KB
    __shared__ unsigned short Ws[128 * 64];    // 16 KB

    const int tid  = threadIdx.x;
    const int lane = tid & 63;
    const int wv_  = tid >> 6;                 // N-strip of 32
    const int quad = lane >> 4, l16 = lane & 15;

    floatx4 acc[4][2];
#pragma unroll
    for (int i = 0; i < 4; ++i)
#pragma unroll
        for (int j = 0; j < 2; ++j) acc[i][j] = (floatx4){0.f, 0.f, 0.f, 0.f};

    for (int k0 = 0; k0 < 768; k0 += 64) {
        __syncthreads();
#pragma unroll
        for (int r = 0; r < 2; ++r) {
            const int idx = tid + 256 * r;     // 0..511: A 64 rows x 8 chunks
            const int row = idx >> 3, cL = idx & 7, cD = cL ^ (row & 7);
            __builtin_amdgcn_global_load_lds(
                (__attribute__((address_space(1))) void*)(A + (size_t)(m0 + row) * 768 + k0 + cD * 8),
                (__attribute__((address_space(3))) void*)&As[idx * 8], 16, 0, 0);
        }
#pragma unroll
        for (int r = 0; r < 4; ++r) {
            const int idx = tid + 256 * r;     // 0..1023: W 128 rows x 8 chunks
            const int row = idx >> 3, cL = idx & 7, cD = cL ^ (row & 7);
            __builtin_amdgcn_global_load_lds(
                (__attribute__((address_space(1))) void*)(W + (size_t)(n0 + row) * 768 + k0 + cD * 8),
                (__attribute__((address_space(3))) void*)&Ws[idx * 8], 16, 0, 0);
        }
        __syncthreads();

        bf16x8 a[4][2], b[2][2];
#pragma unroll
        for (int mi = 0; mi < 4; ++mi)
#pragma unroll
            for (int kc = 0; kc < 2; ++kc)
                a[mi][kc] = lds8(As, mi * 16 + l16, kc * 4 + quad);
#pragma unroll
        for (int ni = 0; ni < 2; ++ni)
#pragma unroll
            for (int kc = 0; kc < 2; ++kc)
                b[ni][kc] = lds8(Ws, wv_ * 32 + ni * 16 + l16, kc * 4 + quad);
#pragma unroll
        for (int mi = 0; mi < 4; ++mi)
#pragma unroll
            for (int ni = 0; ni < 2; ++ni)
#pragma unroll
                for (int kc = 0; kc < 2; ++kc)
                    acc[mi][ni] = __builtin_amdgcn_mfma_f32_16x16x32_bf16(
                        a[mi][kc], b[ni][kc], acc[mi][ni], 0, 0, 0);
    }

#pragma unroll
    for (int ni = 0; ni < 2; ++ni) {
        const int n = n0 + wv_ * 32 + ni * 16 + l16;
        const float bn = bias[n];
#pragma unroll
        for (int mi = 0; mi < 4; ++mi) {
            const int mbase = m0 + mi * 16 + quad * 4;
            if (z == 2) {
                const int bb = mbase / S_, s = mbase - bb * S_;
                const int h = n >> 6, hd = n & 63;
                ushort4 o;
                o.x = f2bf(acc[mi][ni][0] + bn);
                o.y = f2bf(acc[mi][ni][1] + bn);
                o.z = f2bf(acc[mi][ni][2] + bn);
                o.w = f2bf(acc[mi][ni][3] + bn);
                *(ushort4*)&C[(((size_t)(bb * H_ + h) << 6) + hd) * S_ + s] = o;
            } else if (z < 2) {
#pragma unroll
                for (int reg = 0; reg < 4; ++reg) {
                    const int m = mbase + reg;
                    const int bb = m / S_, s = m - bb * S_;
                    const int h = n >> 6, hd = n & 63;
                    C[(((size_t)(bb * H_ + h) * S_ + s) << 6) + hd] =
                        f2bf(acc[mi][ni][reg] + bn);
                }
            } else {
#pragma unroll
                for (int reg = 0; reg < 4; ++reg)
                    C[(size_t)(mbase + reg) * 768 + n] = f2bf(acc[mi][ni][reg] + bn);
            }
        }
    }
}

// ---------------------------------------------------------------------------
// Output projection: 64x128 tile, SPLIT-K x2 (kb = K half), grid = 576.
// Both halves atomicAdd fp32 into d_out (pre-zeroed); bias added by kb==0.
// ---------------------------------------------------------------------------
__global__ __launch_bounds__(256) void gemm_out(
    const unsigned short* __restrict__ A, const unsigned short* __restrict__ W,
    const float* __restrict__ bias, float* __restrict__ C)
{
    const int bid = blockIdx.x;
    const int kb = bid & 1;
    const int t  = bid >> 1;
    const int mt = t / 6, nt = t - mt * 6;
    const int m0 = mt * 64, n0 = nt * 128;

    __shared__ unsigned short As[64 * 64];
    __shared__ unsigned short Ws[128 * 64];

    const int tid  = threadIdx.x;
    const int lane = tid & 63;
    const int wv_  = tid >> 6;
    const int quad = lane >> 4, l16 = lane & 15;

    floatx4 acc[4][2];
#pragma unroll
    for (int i = 0; i < 4; ++i)
#pragma unroll
        for (int j = 0; j < 2; ++j) acc[i][j] = (floatx4){0.f, 0.f, 0.f, 0.f};

    const int kbeg = kb * 384, kend = kbeg + 384;
    for (int k0 = kbeg; k0 < kend; k0 += 64) {
        __syncthreads();
#pragma unroll
        for (int r = 0; r < 2; ++r) {
            const int idx = tid + 256 * r;
            const int row = idx >> 3, cL = idx & 7, cD = cL ^ (row & 7);
            __builtin_amdgcn_global_load_lds(
                (__attribute__((address_space(1))) void*)(A + (size_t)(m0 + row) * 768 + k0 + cD * 8),
                (__attribute__((address_space(3))) void*)&As[idx * 8], 16, 0, 0);
        }
#pragma unroll
        for (int r = 0; r < 4; ++r) {
            const int idx = tid + 256 * r;
            const int row = idx >> 3, cL = idx & 7, cD = cL ^ (row & 7);
            __builtin_amdgcn_global_load_lds(
                (__attribute__((address_space(1))) void*)(W + (size_t)(n0 + row) * 768 + k0 + cD * 8),
                (__attribute__((address_space(3))) void*)&Ws[idx * 8], 16, 0, 0);
        }
        __syncthreads();

        bf16x8 a[4][2], b[2][2];
#pragma unroll
        for (int mi = 0; mi < 4; ++mi)
#pragma unroll
            for (int kc = 0; kc < 2; ++kc)
                a[mi][kc] = lds8(As, mi * 16 + l16, kc * 4 + quad);
#pragma unroll
        for (int ni = 0; ni < 2; ++ni)
#pragma unroll
            for (int kc = 0; kc < 2; ++kc)
                b[ni][kc] = lds8(Ws, wv_ * 32 + ni * 16 + l16, kc * 4 + quad);
#pragma unroll
        for (int mi = 0; mi < 4; ++mi)
#pragma unroll
            for (int ni = 0; ni < 2; ++ni)
#pragma unroll
                for (int kc = 0; kc < 2; ++kc)
                    acc[mi][ni] = __builtin_amdgcn_mfma_f32_16x16x32_bf16(
                        a[mi][kc], b[ni][kc], acc[mi][ni], 0, 0, 0);
    }

#pragma unroll
    for (int ni = 0; ni < 2; ++ni) {
        const int n = n0 + wv_ * 32 + ni * 16 + l16;
        const float bn = (kb == 0) ? bias[n] : 0.f;
#pragma unroll
        for (int mi = 0; mi < 4; ++mi)
#pragma unroll
            for (int reg = 0; reg < 4; ++reg) {
                const int m = m0 + mi * 16 + quad * 4 + reg;
                atomicAdd(&C[(size_t)m * 768 + n], acc[mi][ni][reg] + bn);
            }
    }
}

// ---------------------------------------------------------------------------
// MFMA flash attention, R15 FINAL (proven 57.6/58.0 us on two good boards):
// register softmax, guarded scatter, split-j 6, PK/PQ staged via
// global_load_lds (DMA), Q/K/Vt direct, c2c pre-barrier to cover staging.
// LDS = 49 KB -> 3 blocks/CU. grid = (6,12,48); 256 thr. ONE barrier.
// L2-lifetime law (verified x3 by R16/R18/R20): any variant that extends
// per-block lifetime or working-set (staged K/Vt, 2 batches/block, 3
// j-tiles/block) collapses inter-block L2 reuse -> 1.6-2.4x HBM traffic.
// This structure -- 3456 short-lived single-tile blocks -- is the optimum
// of the explored neighborhood.
// ---------------------------------------------------------------------------
__global__ __launch_bounds__(256, 3) void attn_mfma(
    const unsigned short* __restrict__ qg, const unsigned short* __restrict__ kg,
    const unsigned short* __restrict__ vtg,
    const unsigned short* __restrict__ pkg, const unsigned short* __restrict__ pqg,
    const int* __restrict__ seg, const float* __restrict__ sep,
    const int* __restrict__ mask,
    const float* __restrict__ same_bias, const float* __restrict__ cross_bias,
    const float* __restrict__ sep_scale, const float* __restrict__ sep_decay,
    unsigned short* __restrict__ part_O, float* __restrict__ part_ml)
{
    __shared__ unsigned short PKs[128 * 64];   // 16 KB, swizzled chunks
    __shared__ unsigned short PQs[128 * 64];   // 16 KB
    __shared__ float CP[64 * 68];              // 17 KB score tile

    const int tid  = threadIdx.x;
    const int lane = tid & 63, w = tid >> 6;
    const int l16  = lane & 15, quad = lane >> 4;
    const int it = blockIdx.x, h = blockIdx.y;
    const int b  = blockIdx.z / 6, jt = blockIdx.z - 6 * b;
    const int i0 = it * 64, j0 = jt * 64;
    const size_t bh = (size_t)(b * H_ + h);

    const unsigned short* kbase  = kg  + bh * S_ * 64;
    const unsigned short* vtbase = vtg + bh * 64 * S_;
    const int dbase = i0 - j0 + 320;           // pk/pq window base (0..640)

    // ---- stage PK + PQ (128 rows x 128B each) via global_load_lds DMA ----
#pragma unroll
    for (int r = 0; r < 4; ++r) {
        const int idx = tid + 256 * r;         // 0..1023: 128 rows x 8 chunks
        const int srow = idx >> 3, cL = idx & 7, cD = cL ^ (srow & 7);
        const size_t go = (size_t)(dbase + srow) * 768 + h * 64 + cD * 8;
        __builtin_amdgcn_global_load_lds(
            (__attribute__((address_space(1))) void*)(pkg + go),
            (__attribute__((address_space(3))) void*)&PKs[idx * 8], 16, 0, 0);
        __builtin_amdgcn_global_load_lds(
            (__attribute__((address_space(1))) void*)(pqg + go),
            (__attribute__((address_space(3))) void*)&PQs[idx * 8], 16, 0, 0);
    }

    // ---- direct loads (fly during staging): Q, K, Vt fragments ----
    bf16x8 qf[2];
#pragma unroll
    for (int ks = 0; ks < 2; ++ks)
        qf[ks] = gld8(qg + (bh * S_ + i0 + 16 * w + l16) * 64 + ks * 32 + quad * 8);

    bf16x8 kf[4][2];
#pragma unroll
    for (int nj = 0; nj < 4; ++nj)
#pragma unroll
        for (int ks = 0; ks < 2; ++ks)
            kf[nj][ks] = gld8(kbase + (size_t)(j0 + 16 * nj + l16) * 64
                              + ks * 32 + quad * 8);

    bf16x8 vtf[4][2];
#pragma unroll
    for (int nd = 0; nd < 4; ++nd)
#pragma unroll
        for (int ks = 0; ks < 2; ++ks)
            vtf[nd][ks] = gld8(vtbase + (size_t)(16 * nd + l16) * S_
                               + j0 + ks * 32 + quad * 8);

    // ---- metadata (also in flight) ----
    const int row = 16 * w + l16;              // softmax row this lane owns
    const float aii = fabsf(sep[b * S_ + i0 + row]);
    const int   sii = seg[b * S_ + i0 + row];
    const float* sepj = sep  + b * S_ + j0;
    const int*   segj = seg  + b * S_ + j0;
    const int*   mskj = mask + b * S_ + j0;
    float ajv[16]; int sjv[16], mkv[16];
    *(float4*)&ajv[0]  = *(const float4*)&sepj[quad * 8];
    *(float4*)&ajv[4]  = *(const float4*)&sepj[quad * 8 + 4];
    *(float4*)&ajv[8]  = *(const float4*)&sepj[32 + quad * 8];
    *(float4*)&ajv[12] = *(const float4*)&sepj[32 + quad * 8 + 4];
    *(int4*)&sjv[0]  = *(const int4*)&segj[quad * 8];
    *(int4*)&sjv[4]  = *(const int4*)&segj[quad * 8 + 4];
    *(int4*)&sjv[8]  = *(const int4*)&segj[32 + quad * 8];
    *(int4*)&sjv[12] = *(const int4*)&segj[32 + quad * 8 + 4];
    *(int4*)&mkv[0]  = *(const int4*)&mskj[quad * 8];
    *(int4*)&mkv[4]  = *(const int4*)&mskj[quad * 8 + 4];
    *(int4*)&mkv[8]  = *(const int4*)&mskj[32 + quad * 8];
    *(int4*)&mkv[12] = *(const int4*)&mskj[32 + quad * 8 + 4];

    const float sb  = same_bias[h];
    const float cb  = cross_bias[h];
    const float ssc = sep_scale[h];
    const float sd  = sep_decay[h];
    const float dec = fmaxf(sd, 0.f) + log1pf(__expf(-fabsf(sd))) + 1e-4f;
    const float isc = 0.07216878364870323f;    // 1/sqrt(64*3)

    // bias precompute (VALU work during staging flight)
    float biasv[16]; unsigned mkbits = 0;
#pragma unroll
    for (int e = 0; e < 16; ++e) {
        const float gap = fabsf(aii - fabsf(ajv[e]));
        biasv[e] = (sii == sjv[e]) ? sb : cb + __expf(-gap * dec) * ssc;
        mkbits |= (mkv[e] != 0 ? 1u : 0u) << e;
    }

    // ---- c2c (needs only qf,kf): runs BEFORE the barrier, covers staging ----
#pragma unroll
    for (int nj = 0; nj < 4; ++nj) {
        floatx4 acc = (floatx4){0.f, 0.f, 0.f, 0.f};
#pragma unroll
        for (int ks = 0; ks < 2; ++ks)
            acc = __builtin_amdgcn_mfma_f32_16x16x32_bf16(qf[ks], kf[nj][ks], acc, 0, 0, 0);
#pragma unroll
        for (int reg = 0; reg < 4; ++reg) {
            const int ii = 16 * w + quad * 4 + reg;
            CP[ii * 68 + 16 * nj + l16] = acc[reg];
        }
    }

    __syncthreads();   // the ONE barrier: PK/PQ staging complete

    // ---- c2p (rows strip w): frags nd = w..w+4, scatter jj = ii-ddloc+63 ----
#pragma unroll
    for (int f = 0; f < 5; ++f) {
        const int nd = w + f;
        floatx4 acc = (floatx4){0.f, 0.f, 0.f, 0.f};
#pragma unroll
        for (int ks = 0; ks < 2; ++ks) {
            bf16x8 bf = lds8(PKs, 16 * nd + l16, ks * 4 + quad);
            acc = __builtin_amdgcn_mfma_f32_16x16x32_bf16(qf[ks], bf, acc, 0, 0, 0);
        }
        const int ddloc = 16 * nd + l16;
#pragma unroll
        for (int reg = 0; reg < 4; ++reg) {
            const int ii = 16 * w + quad * 4 + reg;
            const int jj = ii - ddloc + 63;
            if (jj >= 0 && jj < 64)
                CP[ii * 68 + jj] += acc[reg];      // unique writer per cell
        }
    }

    // ---- p2c (rows strip w): A=PQ (m=ddloc), B=K (n=jj) ----
#pragma unroll
    for (int f = 0; f < 5; ++f) {
        const int nd = w + f;
        bf16x8 pqf[2];
#pragma unroll
        for (int ks = 0; ks < 2; ++ks)
            pqf[ks] = lds8(PQs, 16 * nd + l16, ks * 4 + quad);
#pragma unroll
        for (int g = 0; g < 2; ++g) {
            const int nj = (g == 0) ? (3 - f) : (4 - f);
            if (nj < 0 || nj > 3) continue;
            floatx4 acc = (floatx4){0.f, 0.f, 0.f, 0.f};
#pragma unroll
            for (int ks = 0; ks < 2; ++ks)
                acc = __builtin_amdgcn_mfma_f32_16x16x32_bf16(pqf[ks], kf[nj][ks], acc, 0, 0, 0);
            const int jj = 16 * nj + l16;
#pragma unroll
            for (int reg = 0; reg < 4; ++reg) {
                const int ddloc = 16 * nd + quad * 4 + reg;
                const int ii = ddloc + jj - 63;
                if (ii >= 16 * w && ii < 16 * w + 16)
                    CP[ii * 68 + jj] += acc[reg];  // unique writer per cell
            }
        }
    }

    // ---- register softmax: lane owns row `row`, its 16 PV-frag cols ----
    floatx4 cp0 = *(const floatx4*)&CP[row * 68 + quad * 8];
    floatx4 cp1 = *(const floatx4*)&CP[row * 68 + quad * 8 + 4];
    floatx4 cp2 = *(const floatx4*)&CP[row * 68 + 32 + quad * 8];
    floatx4 cp3 = *(const floatx4*)&CP[row * 68 + 32 + quad * 8 + 4];

    float lg[16];
    float tmax = -INFINITY;
#pragma unroll
    for (int e = 0; e < 16; ++e) {
        const float cpv = (e < 4) ? cp0[e] : (e < 8) ? cp1[e - 4]
                        : (e < 12) ? cp2[e - 8] : cp3[e - 12];
        float xv = cpv * isc + biasv[e];
        if (!((mkbits >> e) & 1u)) xv = -9.0e15f;
        lg[e] = xv;
        tmax = fmaxf(tmax, xv);
    }
    tmax = fmaxf(tmax, __shfl_xor(tmax, 16));
    tmax = fmaxf(tmax, __shfl_xor(tmax, 32));

    float rs = 0.f;
    unsigned int pk32[8];
#pragma unroll
    for (int e = 0; e < 8; ++e) {
        const float e0 = __expf(lg[2 * e]     - tmax);
        const float e1 = __expf(lg[2 * e + 1] - tmax);
        rs += e0 + e1;
        pk32[e] = (unsigned)f2bf(e0) | ((unsigned)f2bf(e1) << 16);
    }
    rs += __shfl_xor(rs, 16);
    rs += __shfl_xor(rs, 32);

    float* pml = part_ml + (size_t)(jt * 576 + ((b * H_ + h) * 6 + it)) * 128;
    if (quad == 0) {
        pml[row]      = tmax;
        pml[64 + row] = rs;
    }

    // ---- PV: O = P x Vt; pA straight from registers, vtf preloaded ----
    bf16x8 pA[2];
    pA[0] = __builtin_bit_cast(bf16x8, (ux4){pk32[0], pk32[1], pk32[2], pk32[3]});
    pA[1] = __builtin_bit_cast(bf16x8, (ux4){pk32[4], pk32[5], pk32[6], pk32[7]});
    floatx4 O[4];
#pragma unroll
    for (int nd = 0; nd < 4; ++nd) {
        O[nd] = (floatx4){0.f, 0.f, 0.f, 0.f};
#pragma unroll
        for (int ks = 0; ks < 2; ++ks)
            O[nd] = __builtin_amdgcn_mfma_f32_16x16x32_bf16(pA[ks], vtf[nd][ks], O[nd], 0, 0, 0);
    }

    // ---- epilogue: write unnormalized partial O ----
    unsigned short* pO = part_O + (size_t)(jt * 576 + ((b * H_ + h) * 6 + it)) * 4096;
#pragma unroll
    for (int nd = 0; nd < 4; ++nd) {
        const int d = 16 * nd + l16;
#pragma unroll
        for (int reg = 0; reg < 4; ++reg) {
            const int ii = 16 * w + quad * 4 + reg;
            pO[ii * 64 + d] = f2bf(O[nd][reg]);
        }
    }
}

// ---------------------------------------------------------------------------
// Merge the 6 split-j partials -> vals (bf16, (B,S,E)). grid=576, 256 thr.
// ---------------------------------------------------------------------------
__global__ __launch_bounds__(256) void merge_attn(
    const unsigned short* __restrict__ part_O, const float* __restrict__ part_ml,
    unsigned short* __restrict__ vals)
{
    const int idx = blockIdx.x;                 // ((b*H+h)*6+it)
    const int b  = idx / (H_ * 6);
    const int r  = idx - b * H_ * 6;
    const int h  = r / 6, it = r - h * 6;
    const int tid = threadIdx.x;
    const int ii = tid >> 2, c = (tid & 3) * 16;

    float m[6], l[6];
#pragma unroll
    for (int jc = 0; jc < 6; ++jc) {
        const float* pml = part_ml + (size_t)(jc * 576 + idx) * 128;
        m[jc] = pml[ii];
        l[jc] = pml[64 + ii];
    }
    float M = m[0];
#pragma unroll
    for (int jc = 1; jc < 6; ++jc) M = fmaxf(M, m[jc]);
    float wsum = 0.f, wc[6];
#pragma unroll
    for (int jc = 0; jc < 6; ++jc) {
        wc[jc] = __expf(m[jc] - M);
        wsum += wc[jc] * l[jc];
    }
    const float inv = (wsum > 0.f) ? 1.f / wsum : 0.f;

    float o[16];
#pragma unroll
    for (int e = 0; e < 16; ++e) o[e] = 0.f;
#pragma unroll
    for (int jc = 0; jc < 6; ++jc) {
        const unsigned short* pO = part_O + ((size_t)(jc * 576 + idx)) * 4096
                                 + ii * 64 + c;
        ux4 u0 = *(const ux4*)pO;
        ux4 u1 = *(const ux4*)(pO + 8);
        const unsigned short* us0 = (const unsigned short*)&u0;
        const unsigned short* us1 = (const unsigned short*)&u1;
#pragma unroll
        for (int e = 0; e < 8; ++e) {
            o[e]     += wc[jc] * bf2f(us0[e]);
            o[8 + e] += wc[jc] * bf2f(us1[e]);
        }
    }
    ushort4 w0, w1, w2, w3;
#pragma unroll
    for (int e = 0; e < 4; ++e) {
        ((unsigned short*)&w0)[e] = f2bf(o[e] * inv);
        ((unsigned short*)&w1)[e] = f2bf(o[4 + e] * inv);
        ((unsigned short*)&w2)[e] = f2bf(o[8 + e] * inv);
        ((unsigned short*)&w3)[e] = f2bf(o[12 + e] * inv);
    }
    unsigned short* dst = vals + ((size_t)(b * S_ + it * 64 + ii)) * E_ + h * 64 + c;
    *(ushort4*)(dst)      = w0;
    *(ushort4*)(dst + 4)  = w1;
    *(ushort4*)(dst + 8)  = w2;
    *(ushort4*)(dst + 12) = w3;
}

// ---------------------------------------------------------------------------
// Launcher. Workspace (shorts unless noted): xb 2359296; 7x589824 weights/rel;
// qb,kb,vtb 3x2359296; pkb,pqb 2x589824; valsb 2359296; part_O 6x576x4096;
// part_ml fp32 6x576x128. ~69 MiB.
// ---------------------------------------------------------------------------
extern "C" void kernel_launch(void* const* d_in, const int* in_sizes, int n_in,
                              void* d_out, int out_size, void* d_ws, size_t ws_size,
                              hipStream_t stream)
{
    const float* x         = (const float*)d_in[0];
    const int*   mask      = (const int*)d_in[1];
    const int*   seg       = (const int*)d_in[2];
    const float* sep       = (const float*)d_in[3];
    const float* Wq        = (const float*)d_in[4];
    const float* bq        = (const float*)d_in[5];
    const float* Wk        = (const float*)d_in[6];
    const float* bk        = (const float*)d_in[7];
    const float* Wv        = (const float*)d_in[8];
    const float* bv        = (const float*)d_in[9];
    const float* rel_emb   = (const float*)d_in[10];
    const float* Wpk       = (const float*)d_in[11];
    const float* bpk       = (const float*)d_in[12];
    const float* Wpq       = (const float*)d_in[13];
    const float* bpq       = (const float*)d_in[14];
    const float* same_bias = (const float*)d_in[15];
    const float* cross_bias= (const float*)d_in[16];
    const float* sep_scale = (const float*)d_in[17];
    const float* sep_decay = (const float*)d_in[18];
    const float* Wo        = (const float*)d_in[19];
    const float* bo        = (const float*)d_in[20];

    const size_t QKVN = (size_t)B_ * S_ * E_;   // 2359296
    const size_t WN   = (size_t)768 * 768;      //  589824

    unsigned short* xb    = (unsigned short*)d_ws;
    unsigned short* wqb   = xb   + QKVN;
    unsigned short* wkb   = wqb  + WN;
    unsigned short* wvb   = wkb  + WN;
    unsigned short* wob   = wvb  + WN;
    unsigned short* wpkb  = wob  + WN;
    unsigned short* wpqb  = wpkb + WN;
    unsigned short* relb  = wpqb + WN;
    unsigned short* qb    = relb + WN;
    unsigned short* kb    = qb   + QKVN;
    unsigned short* vtb   = kb   + QKVN;
    unsigned short* pkb   = vtb  + QKVN;
    unsigned short* pqb   = pkb  + WN;
    unsigned short* valsb = pqb  + WN;
    unsigned short* partO = valsb + QKVN;                       // 6*576*4096 shorts
    float*          partml= (float*)(partO + (size_t)6 * 576 * 4096);

    // 0) pre-zero d_out for gemm_out's split-K atomic accumulation
    hipMemsetAsync(d_out, 0, (size_t)out_size, stream);

    // 1) convert all operands to bf16
    convert_all<<<dim3(576, 11), 256, 0, stream>>>(
        x, Wq, Wk, Wv, Wo, Wpk, Wpq, rel_emb + (size_t)128 * D_,
        xb, wqb, wkb, wvb, wob, wpkb, wpqb, relb);

    // 2) fused Q/K/Vt/pk/pq projections (64x128 tiles, 1008 blocks)
    proj_all<<<dim3(1008), 256, 0, stream>>>(
        xb, relb, wqb, wkb, wvb, wpkb, wpqb,
        bq, bk, bv, bpk, bpq, qb, kb, vtb, pkb, pqb);

    // 3) MFMA flash attention (R15 proven version), split-j x6
    attn_mfma<<<dim3(6, 12, 48), 256, 0, stream>>>(
        qb, kb, vtb, pkb, pqb, seg, sep, mask,
        same_bias, cross_bias, sep_scale, sep_decay, partO, partml);

    // 4) merge partials -> valsb
    merge_attn<<<dim3(576), 256, 0, stream>>>(partO, partml, valsb);

    // 5) output projection (64x128 tiles, SPLIT-K x2, 576 blocks, atomic)
    gemm_out<<<dim3(576), 256, 0, stream>>>(valsb, wob, bo, (float*)d_out);
}

// Round 13
// 201.468 us; speedup vs baseline: 1.1905x; 1.0506x over previous
//
#include <hip/hip_runtime.h>
#include <math.h>

// Problem constants
#define B_  8
#define S_  384
#define H_  12
#define HD_ 64
#define E_  768
#define D_  768

typedef float  floatx4 __attribute__((ext_vector_type(4)));
typedef __bf16 bf16x8  __attribute__((ext_vector_type(8)));
typedef unsigned int ux4 __attribute__((ext_vector_type(4)));

__device__ __forceinline__ unsigned short f2bf(float f) {
    union { float f; unsigned u; } x; x.f = f;
    unsigned r = x.u + 0x7fff + ((x.u >> 16) & 1);
    return (unsigned short)(r >> 16);
}
__device__ __forceinline__ float bf2f(unsigned short u) {
    union { unsigned u; float f; } x; x.u = ((unsigned)u) << 16;
    return x.f;
}
__device__ __forceinline__ bf16x8 gld8(const unsigned short* p) {
    return __builtin_bit_cast(bf16x8, *(const ux4*)p);
}
// swizzled chunk address (shorts) for 128B-row tiles staged via global_load_lds
__device__ __forceinline__ int tadr(int row, int cD) {
    return (row * 8 + (cD ^ (row & 7))) * 8;
}
__device__ __forceinline__ bf16x8 lds8(const unsigned short* base, int row, int cD) {
    return __builtin_bit_cast(bf16x8, *(const ux4*)(base + tadr(row, cD)));
}

// ---------------------------------------------------------------------------
// Fused fp32 -> bf16 convert. grid=(576,11).
// ---------------------------------------------------------------------------
__global__ __launch_bounds__(256) void convert_all(
    const float* __restrict__ x,
    const float* __restrict__ Wq, const float* __restrict__ Wk,
    const float* __restrict__ Wv, const float* __restrict__ Wo,
    const float* __restrict__ Wpk, const float* __restrict__ Wpq,
    const float* __restrict__ rel128,
    unsigned short* __restrict__ xb,
    unsigned short* __restrict__ wqb, unsigned short* __restrict__ wkb,
    unsigned short* __restrict__ wvb, unsigned short* __restrict__ wob,
    unsigned short* __restrict__ wpkb, unsigned short* __restrict__ wpqb,
    unsigned short* __restrict__ relb)
{
    const int seg = blockIdx.y;
    const int e = (blockIdx.x * 256 + threadIdx.x) * 4;
    const float* src;
    unsigned short* dst;
    if (seg < 4)       { src = x + (size_t)seg * 589824; dst = xb + (size_t)seg * 589824; }
    else if (seg == 4) { src = Wq;  dst = wqb; }
    else if (seg == 5) { src = Wk;  dst = wkb; }
    else if (seg == 6) { src = Wv;  dst = wvb; }
    else if (seg == 7) { src = Wo;  dst = wob; }
    else if (seg == 8) { src = Wpk; dst = wpkb; }
    else if (seg == 9) { src = Wpq; dst = wpqb; }
    else               { src = rel128; dst = relb; }

    float4 v;
    if (seg == 10 && e >= 767 * 768) v = make_float4(0.f, 0.f, 0.f, 0.f);
    else                             v = *(const float4*)(src + e);
    ushort4 o;
    o.x = f2bf(v.x); o.y = f2bf(v.y); o.z = f2bf(v.z); o.w = f2bf(v.w);
    *(ushort4*)(dst + e) = o;
}

// ---------------------------------------------------------------------------
// Projection GEMMs (Q,K,Vt,pk,pq), 64x128 tile, BK=64, flat grid of 1008:
//   bid <  864 : z = bid/288 (Q,K,Vt), 48 m-tiles x 6 n-tiles
//   bid >= 864 : z = 3 + (bid-864)/72 (pk,pq), 12 m-tiles x 6 n-tiles
// ---------------------------------------------------------------------------
__global__ __launch_bounds__(256) void proj_all(
    const unsigned short* __restrict__ xb, const unsigned short* __restrict__ relb,
    const unsigned short* __restrict__ wq, const unsigned short* __restrict__ wk,
    const unsigned short* __restrict__ wv, const unsigned short* __restrict__ wpk,
    const unsigned short* __restrict__ wpq,
    const float* __restrict__ bq, const float* __restrict__ bk,
    const float* __restrict__ bv, const float* __restrict__ bpk,
    const float* __restrict__ bpq,
    unsigned short* __restrict__ qb, unsigned short* __restrict__ kb,
    unsigned short* __restrict__ vtb, unsigned short* __restrict__ pkb,
    unsigned short* __restrict__ pqb)
{
    const int bid = blockIdx.x;
    int z, mt, nt;
    if (bid < 864) {
        z = bid / 288; const int r = bid - z * 288; mt = r / 6; nt = r - mt * 6;
    } else {
        const int r2 = bid - 864; z = 3 + r2 / 72;
        const int r = r2 % 72; mt = r / 6; nt = r - mt * 6;
    }
    const int m0 = mt * 64, n0 = nt * 128;

    const unsigned short* A = (z < 3) ? xb : relb;
    const unsigned short* W = (z == 0) ? wq : (z == 1) ? wk : (z == 2) ? wv
                            : (z == 3) ? wpk : wpq;
    const float* bias = (z == 0) ? bq : (z == 1) ? bk : (z == 2) ? bv
                      : (z == 3) ? bpk : bpq;
    unsigned short* C = (z == 0) ? qb : (z == 1) ? kb : (z == 2) ? vtb
                      : (z == 3) ? pkb : pqb;

    __shared__ unsigned short As[64 * 64];     //  8 KB
    __shared__ unsigned short Ws[128 * 64];    // 16 KB

    const int tid  = threadIdx.x;
    const int lane = tid & 63;
    const int wv_  = tid >> 6;                 // N-strip of 32
    const int quad = lane >> 4, l16 = lane & 15;

    floatx4 acc[4][2];
#pragma unroll
    for (int i = 0; i < 4; ++i)
#pragma unroll
        for (int j = 0; j < 2; ++j) acc[i][j] = (floatx4){0.f, 0.f, 0.f, 0.f};

    for (int k0 = 0; k0 < 768; k0 += 64) {
        __syncthreads();
#pragma unroll
        for (int r = 0; r < 2; ++r) {
            const int idx = tid + 256 * r;     // 0..511: A 64 rows x 8 chunks
            const int row = idx >> 3, cL = idx & 7, cD = cL ^ (row & 7);
            __builtin_amdgcn_global_load_lds(
                (__attribute__((address_space(1))) void*)(A + (size_t)(m0 + row) * 768 + k0 + cD * 8),
                (__attribute__((address_space(3))) void*)&As[idx * 8], 16, 0, 0);
        }
#pragma unroll
        for (int r = 0; r < 4; ++r) {
            const int idx = tid + 256 * r;     // 0..1023: W 128 rows x 8 chunks
            const int row = idx >> 3, cL = idx & 7, cD = cL ^ (row & 7);
            __builtin_amdgcn_global_load_lds(
                (__attribute__((address_space(1))) void*)(W + (size_t)(n0 + row) * 768 + k0 + cD * 8),
                (__attribute__((address_space(3))) void*)&Ws[idx * 8], 16, 0, 0);
        }
        __syncthreads();

        bf16x8 a[4][2], b[2][2];
#pragma unroll
        for (int mi = 0; mi < 4; ++mi)
#pragma unroll
            for (int kc = 0; kc < 2; ++kc)
                a[mi][kc] = lds8(As, mi * 16 + l16, kc * 4 + quad);
#pragma unroll
        for (int ni = 0; ni < 2; ++ni)
#pragma unroll
            for (int kc = 0; kc < 2; ++kc)
                b[ni][kc] = lds8(Ws, wv_ * 32 + ni * 16 + l16, kc * 4 + quad);
#pragma unroll
        for (int mi = 0; mi < 4; ++mi)
#pragma unroll
            for (int ni = 0; ni < 2; ++ni)
#pragma unroll
                for (int kc = 0; kc < 2; ++kc)
                    acc[mi][ni] = __builtin_amdgcn_mfma_f32_16x16x32_bf16(
                        a[mi][kc], b[ni][kc], acc[mi][ni], 0, 0, 0);
    }

#pragma unroll
    for (int ni = 0; ni < 2; ++ni) {
        const int n = n0 + wv_ * 32 + ni * 16 + l16;
        const float bn = bias[n];
#pragma unroll
        for (int mi = 0; mi < 4; ++mi) {
            const int mbase = m0 + mi * 16 + quad * 4;
            if (z == 2) {
                const int bb = mbase / S_, s = mbase - bb * S_;
                const int h = n >> 6, hd = n & 63;
                ushort4 o;
                o.x = f2bf(acc[mi][ni][0] + bn);
                o.y = f2bf(acc[mi][ni][1] + bn);
                o.z = f2bf(acc[mi][ni][2] + bn);
                o.w = f2bf(acc[mi][ni][3] + bn);
                *(ushort4*)&C[(((size_t)(bb * H_ + h) << 6) + hd) * S_ + s] = o;
            } else if (z < 2) {
#pragma unroll
                for (int reg = 0; reg < 4; ++reg) {
                    const int m = mbase + reg;
                    const int bb = m / S_, s = m - bb * S_;
                    const int h = n >> 6, hd = n & 63;
                    C[(((size_t)(bb * H_ + h) * S_ + s) << 6) + hd] =
                        f2bf(acc[mi][ni][reg] + bn);
                }
            } else {
#pragma unroll
                for (int reg = 0; reg < 4; ++reg)
                    C[(size_t)(mbase + reg) * 768 + n] = f2bf(acc[mi][ni][reg] + bn);
            }
        }
    }
}

// ---------------------------------------------------------------------------
// Output projection: 64x128 tile, BK=64, grid = 288 (48 m-tiles x 6 n-tiles).
// Direct fp32 stores (non-split-K): the best-measured end-to-end (200.4 us)
// used this form; split-K x2 + memset + atomics was neutral-to-worse.
// ---------------------------------------------------------------------------
__global__ __launch_bounds__(256) void gemm_out(
    const unsigned short* __restrict__ A, const unsigned short* __restrict__ W,
    const float* __restrict__ bias, float* __restrict__ C)
{
    const int mt = blockIdx.x / 6, nt = blockIdx.x - mt * 6;
    const int m0 = mt * 64, n0 = nt * 128;

    __shared__ unsigned short As[64 * 64];
    __shared__ unsigned short Ws[128 * 64];

    const int tid  = threadIdx.x;
    const int lane = tid & 63;
    const int wv_  = tid >> 6;
    const int quad = lane >> 4, l16 = lane & 15;

    floatx4 acc[4][2];
#pragma unroll
    for (int i = 0; i < 4; ++i)
#pragma unroll
        for (int j = 0; j < 2; ++j) acc[i][j] = (floatx4){0.f, 0.f, 0.f, 0.f};

    for (int k0 = 0; k0 < 768; k0 += 64) {
        __syncthreads();
#pragma unroll
        for (int r = 0; r < 2; ++r) {
            const int idx = tid + 256 * r;
            const int row = idx >> 3, cL = idx & 7, cD = cL ^ (row & 7);
            __builtin_amdgcn_global_load_lds(
                (__attribute__((address_space(1))) void*)(A + (size_t)(m0 + row) * 768 + k0 + cD * 8),
                (__attribute__((address_space(3))) void*)&As[idx * 8], 16, 0, 0);
        }
#pragma unroll
        for (int r = 0; r < 4; ++r) {
            const int idx = tid + 256 * r;
            const int row = idx >> 3, cL = idx & 7, cD = cL ^ (row & 7);
            __builtin_amdgcn_global_load_lds(
                (__attribute__((address_space(1))) void*)(W + (size_t)(n0 + row) * 768 + k0 + cD * 8),
                (__attribute__((address_space(3))) void*)&Ws[idx * 8], 16, 0, 0);
        }
        __syncthreads();

        bf16x8 a[4][2], b[2][2];
#pragma unroll
        for (int mi = 0; mi < 4; ++mi)
#pragma unroll
            for (int kc = 0; kc < 2; ++kc)
                a[mi][kc] = lds8(As, mi * 16 + l16, kc * 4 + quad);
#pragma unroll
        for (int ni = 0; ni < 2; ++ni)
#pragma unroll
            for (int kc = 0; kc < 2; ++kc)
                b[ni][kc] = lds8(Ws, wv_ * 32 + ni * 16 + l16, kc * 4 + quad);
#pragma unroll
        for (int mi = 0; mi < 4; ++mi)
#pragma unroll
            for (int ni = 0; ni < 2; ++ni)
#pragma unroll
                for (int kc = 0; kc < 2; ++kc)
                    acc[mi][ni] = __builtin_amdgcn_mfma_f32_16x16x32_bf16(
                        a[mi][kc], b[ni][kc], acc[mi][ni], 0, 0, 0);
    }

#pragma unroll
    for (int ni = 0; ni < 2; ++ni) {
        const int n = n0 + wv_ * 32 + ni * 16 + l16;
        const float bn = bias[n];
#pragma unroll
        for (int mi = 0; mi < 4; ++mi)
#pragma unroll
            for (int reg = 0; reg < 4; ++reg) {
                const int m = m0 + mi * 16 + quad * 4 + reg;
                C[(size_t)m * 768 + n] = acc[mi][ni][reg] + bn;
            }
    }
}

// ---------------------------------------------------------------------------
// MFMA flash attention, R15 FINAL (proven 57.6/58.0/58.7 us on good boards):
// register softmax, guarded scatter, split-j 6, PK/PQ staged via
// global_load_lds (DMA), Q/K/Vt direct, c2c pre-barrier to cover staging.
// LDS = 49 KB -> 3 blocks/CU. grid = (6,12,48); 256 thr. ONE barrier.
// L2-lifetime law (verified x3 by R16/R18/R20): any variant that extends
// per-block lifetime or working-set (staged K/Vt, 2 batches/block, 3
// j-tiles/block) collapses inter-block L2 reuse -> 1.6-2.4x HBM traffic.
// This structure -- 3456 short-lived single-tile blocks -- is the optimum
// of the explored neighborhood.
// ---------------------------------------------------------------------------
__global__ __launch_bounds__(256, 3) void attn_mfma(
    const unsigned short* __restrict__ qg, const unsigned short* __restrict__ kg,
    const unsigned short* __restrict__ vtg,
    const unsigned short* __restrict__ pkg, const unsigned short* __restrict__ pqg,
    const int* __restrict__ seg, const float* __restrict__ sep,
    const int* __restrict__ mask,
    const float* __restrict__ same_bias, const float* __restrict__ cross_bias,
    const float* __restrict__ sep_scale, const float* __restrict__ sep_decay,
    unsigned short* __restrict__ part_O, float* __restrict__ part_ml)
{
    __shared__ unsigned short PKs[128 * 64];   // 16 KB, swizzled chunks
    __shared__ unsigned short PQs[128 * 64];   // 16 KB
    __shared__ float CP[64 * 68];              // 17 KB score tile

    const int tid  = threadIdx.x;
    const int lane = tid & 63, w = tid >> 6;
    const int l16  = lane & 15, quad = lane >> 4;
    const int it = blockIdx.x, h = blockIdx.y;
    const int b  = blockIdx.z / 6, jt = blockIdx.z - 6 * b;
    const int i0 = it * 64, j0 = jt * 64;
    const size_t bh = (size_t)(b * H_ + h);

    const unsigned short* kbase  = kg  + bh * S_ * 64;
    const unsigned short* vtbase = vtg + bh * 64 * S_;
    const int dbase = i0 - j0 + 320;           // pk/pq window base (0..640)

    // ---- stage PK + PQ (128 rows x 128B each) via global_load_lds DMA ----
#pragma unroll
    for (int r = 0; r < 4; ++r) {
        const int idx = tid + 256 * r;         // 0..1023: 128 rows x 8 chunks
        const int srow = idx >> 3, cL = idx & 7, cD = cL ^ (srow & 7);
        const size_t go = (size_t)(dbase + srow) * 768 + h * 64 + cD * 8;
        __builtin_amdgcn_global_load_lds(
            (__attribute__((address_space(1))) void*)(pkg + go),
            (__attribute__((address_space(3))) void*)&PKs[idx * 8], 16, 0, 0);
        __builtin_amdgcn_global_load_lds(
            (__attribute__((address_space(1))) void*)(pqg + go),
            (__attribute__((address_space(3))) void*)&PQs[idx * 8], 16, 0, 0);
    }

    // ---- direct loads (fly during staging): Q, K, Vt fragments ----
    bf16x8 qf[2];
#pragma unroll
    for (int ks = 0; ks < 2; ++ks)
        qf[ks] = gld8(qg + (bh * S_ + i0 + 16 * w + l16) * 64 + ks * 32 + quad * 8);

    bf16x8 kf[4][2];
#pragma unroll
    for (int nj = 0; nj < 4; ++nj)
#pragma unroll
        for (int ks = 0; ks < 2; ++ks)
            kf[nj][ks] = gld8(kbase + (size_t)(j0 + 16 * nj + l16) * 64
                              + ks * 32 + quad * 8);

    bf16x8 vtf[4][2];
#pragma unroll
    for (int nd = 0; nd < 4; ++nd)
#pragma unroll
        for (int ks = 0; ks < 2; ++ks)
            vtf[nd][ks] = gld8(vtbase + (size_t)(16 * nd + l16) * S_
                               + j0 + ks * 32 + quad * 8);

    // ---- metadata (also in flight) ----
    const int row = 16 * w + l16;              // softmax row this lane owns
    const float aii = fabsf(sep[b * S_ + i0 + row]);
    const int   sii = seg[b * S_ + i0 + row];
    const float* sepj = sep  + b * S_ + j0;
    const int*   segj = seg  + b * S_ + j0;
    const int*   mskj = mask + b * S_ + j0;
    float ajv[16]; int sjv[16], mkv[16];
    *(float4*)&ajv[0]  = *(const float4*)&sepj[quad * 8];
    *(float4*)&ajv[4]  = *(const float4*)&sepj[quad * 8 + 4];
    *(float4*)&ajv[8]  = *(const float4*)&sepj[32 + quad * 8];
    *(float4*)&ajv[12] = *(const float4*)&sepj[32 + quad * 8 + 4];
    *(int4*)&sjv[0]  = *(const int4*)&segj[quad * 8];
    *(int4*)&sjv[4]  = *(const int4*)&segj[quad * 8 + 4];
    *(int4*)&sjv[8]  = *(const int4*)&segj[32 + quad * 8];
    *(int4*)&sjv[12] = *(const int4*)&segj[32 + quad * 8 + 4];
    *(int4*)&mkv[0]  = *(const int4*)&mskj[quad * 8];
    *(int4*)&mkv[4]  = *(const int4*)&mskj[quad * 8 + 4];
    *(int4*)&mkv[8]  = *(const int4*)&mskj[32 + quad * 8];
    *(int4*)&mkv[12] = *(const int4*)&mskj[32 + quad * 8 + 4];

    const float sb  = same_bias[h];
    const float cb  = cross_bias[h];
    const float ssc = sep_scale[h];
    const float sd  = sep_decay[h];
    const float dec = fmaxf(sd, 0.f) + log1pf(__expf(-fabsf(sd))) + 1e-4f;
    const float isc = 0.07216878364870323f;    // 1/sqrt(64*3)

    // bias precompute (VALU work during staging flight)
    float biasv[16]; unsigned mkbits = 0;
#pragma unroll
    for (int e = 0; e < 16; ++e) {
        const float gap = fabsf(aii - fabsf(ajv[e]));
        biasv[e] = (sii == sjv[e]) ? sb : cb + __expf(-gap * dec) * ssc;
        mkbits |= (mkv[e] != 0 ? 1u : 0u) << e;
    }

    // ---- c2c (needs only qf,kf): runs BEFORE the barrier, covers staging ----
#pragma unroll
    for (int nj = 0; nj < 4; ++nj) {
        floatx4 acc = (floatx4){0.f, 0.f, 0.f, 0.f};
#pragma unroll
        for (int ks = 0; ks < 2; ++ks)
            acc = __builtin_amdgcn_mfma_f32_16x16x32_bf16(qf[ks], kf[nj][ks], acc, 0, 0, 0);
#pragma unroll
        for (int reg = 0; reg < 4; ++reg) {
            const int ii = 16 * w + quad * 4 + reg;
            CP[ii * 68 + 16 * nj + l16] = acc[reg];
        }
    }

    __syncthreads();   // the ONE barrier: PK/PQ staging complete

    // ---- c2p (rows strip w): frags nd = w..w+4, scatter jj = ii-ddloc+63 ----
#pragma unroll
    for (int f = 0; f < 5; ++f) {
        const int nd = w + f;
        floatx4 acc = (floatx4){0.f, 0.f, 0.f, 0.f};
#pragma unroll
        for (int ks = 0; ks < 2; ++ks) {
            bf16x8 bf = lds8(PKs, 16 * nd + l16, ks * 4 + quad);
            acc = __builtin_amdgcn_mfma_f32_16x16x32_bf16(qf[ks], bf, acc, 0, 0, 0);
        }
        const int ddloc = 16 * nd + l16;
#pragma unroll
        for (int reg = 0; reg < 4; ++reg) {
            const int ii = 16 * w + quad * 4 + reg;
            const int jj = ii - ddloc + 63;
            if (jj >= 0 && jj < 64)
                CP[ii * 68 + jj] += acc[reg];      // unique writer per cell
        }
    }

    // ---- p2c (rows strip w): A=PQ (m=ddloc), B=K (n=jj) ----
#pragma unroll
    for (int f = 0; f < 5; ++f) {
        const int nd = w + f;
        bf16x8 pqf[2];
#pragma unroll
        for (int ks = 0; ks < 2; ++ks)
            pqf[ks] = lds8(PQs, 16 * nd + l16, ks * 4 + quad);
#pragma unroll
        for (int g = 0; g < 2; ++g) {
            const int nj = (g == 0) ? (3 - f) : (4 - f);
            if (nj < 0 || nj > 3) continue;
            floatx4 acc = (floatx4){0.f, 0.f, 0.f, 0.f};
#pragma unroll
            for (int ks = 0; ks < 2; ++ks)
                acc = __builtin_amdgcn_mfma_f32_16x16x32_bf16(pqf[ks], kf[nj][ks], acc, 0, 0, 0);
            const int jj = 16 * nj + l16;
#pragma unroll
            for (int reg = 0; reg < 4; ++reg) {
                const int ddloc = 16 * nd + quad * 4 + reg;
                const int ii = ddloc + jj - 63;
                if (ii >= 16 * w && ii < 16 * w + 16)
                    CP[ii * 68 + jj] += acc[reg];  // unique writer per cell
            }
        }
    }

    // ---- register softmax: lane owns row `row`, its 16 PV-frag cols ----
    floatx4 cp0 = *(const floatx4*)&CP[row * 68 + quad * 8];
    floatx4 cp1 = *(const floatx4*)&CP[row * 68 + quad * 8 + 4];
    floatx4 cp2 = *(const floatx4*)&CP[row * 68 + 32 + quad * 8];
    floatx4 cp3 = *(const floatx4*)&CP[row * 68 + 32 + quad * 8 + 4];

    float lg[16];
    float tmax = -INFINITY;
#pragma unroll
    for (int e = 0; e < 16; ++e) {
        const float cpv = (e < 4) ? cp0[e] : (e < 8) ? cp1[e - 4]
                        : (e < 12) ? cp2[e - 8] : cp3[e - 12];
        float xv = cpv * isc + biasv[e];
        if (!((mkbits >> e) & 1u)) xv = -9.0e15f;
        lg[e] = xv;
        tmax = fmaxf(tmax, xv);
    }
    tmax = fmaxf(tmax, __shfl_xor(tmax, 16));
    tmax = fmaxf(tmax, __shfl_xor(tmax, 32));

    float rs = 0.f;
    unsigned int pk32[8];
#pragma unroll
    for (int e = 0; e < 8; ++e) {
        const float e0 = __expf(lg[2 * e]     - tmax);
        const float e1 = __expf(lg[2 * e + 1] - tmax);
        rs += e0 + e1;
        pk32[e] = (unsigned)f2bf(e0) | ((unsigned)f2bf(e1) << 16);
    }
    rs += __shfl_xor(rs, 16);
    rs += __shfl_xor(rs, 32);

    float* pml = part_ml + (size_t)(jt * 576 + ((b * H_ + h) * 6 + it)) * 128;
    if (quad == 0) {
        pml[row]      = tmax;
        pml[64 + row] = rs;
    }

    // ---- PV: O = P x Vt; pA straight from registers, vtf preloaded ----
    bf16x8 pA[2];
    pA[0] = __builtin_bit_cast(bf16x8, (ux4){pk32[0], pk32[1], pk32[2], pk32[3]});
    pA[1] = __builtin_bit_cast(bf16x8, (ux4){pk32[4], pk32[5], pk32[6], pk32[7]});
    floatx4 O[4];
#pragma unroll
    for (int nd = 0; nd < 4; ++nd) {
        O[nd] = (floatx4){0.f, 0.f, 0.f, 0.f};
#pragma unroll
        for (int ks = 0; ks < 2; ++ks)
            O[nd] = __builtin_amdgcn_mfma_f32_16x16x32_bf16(pA[ks], vtf[nd][ks], O[nd], 0, 0, 0);
    }

    // ---- epilogue: write unnormalized partial O ----
    unsigned short* pO = part_O + (size_t)(jt * 576 + ((b * H_ + h) * 6 + it)) * 4096;
#pragma unroll
    for (int nd = 0; nd < 4; ++nd) {
        const int d = 16 * nd + l16;
#pragma unroll
        for (int reg = 0; reg < 4; ++reg) {
            const int ii = 16 * w + quad * 4 + reg;
            pO[ii * 64 + d] = f2bf(O[nd][reg]);
        }
    }
}

// ---------------------------------------------------------------------------
// Merge the 6 split-j partials -> vals (bf16, (B,S,E)). grid=576, 256 thr.
// ---------------------------------------------------------------------------
__global__ __launch_bounds__(256) void merge_attn(
    const unsigned short* __restrict__ part_O, const float* __restrict__ part_ml,
    unsigned short* __restrict__ vals)
{
    const int idx = blockIdx.x;                 // ((b*H+h)*6+it)
    const int b  = idx / (H_ * 6);
    const int r  = idx - b * H_ * 6;
    const int h  = r / 6, it = r - h * 6;
    const int tid = threadIdx.x;
    const int ii = tid >> 2, c = (tid & 3) * 16;

    float m[6], l[6];
#pragma unroll
    for (int jc = 0; jc < 6; ++jc) {
        const float* pml = part_ml + (size_t)(jc * 576 + idx) * 128;
        m[jc] = pml[ii];
        l[jc] = pml[64 + ii];
    }
    float M = m[0];
#pragma unroll
    for (int jc = 1; jc < 6; ++jc) M = fmaxf(M, m[jc]);
    float wsum = 0.f, wc[6];
#pragma unroll
    for (int jc = 0; jc < 6; ++jc) {
        wc[jc] = __expf(m[jc] - M);
        wsum += wc[jc] * l[jc];
    }
    const float inv = (wsum > 0.f) ? 1.f / wsum : 0.f;

    float o[16];
#pragma unroll
    for (int e = 0; e < 16; ++e) o[e] = 0.f;
#pragma unroll
    for (int jc = 0; jc < 6; ++jc) {
        const unsigned short* pO = part_O + ((size_t)(jc * 576 + idx)) * 4096
                                 + ii * 64 + c;
        ux4 u0 = *(const ux4*)pO;
        ux4 u1 = *(const ux4*)(pO + 8);
        const unsigned short* us0 = (const unsigned short*)&u0;
        const unsigned short* us1 = (const unsigned short*)&u1;
#pragma unroll
        for (int e = 0; e < 8; ++e) {
            o[e]     += wc[jc] * bf2f(us0[e]);
            o[8 + e] += wc[jc] * bf2f(us1[e]);
        }
    }
    ushort4 w0, w1, w2, w3;
#pragma unroll
    for (int e = 0; e < 4; ++e) {
        ((unsigned short*)&w0)[e] = f2bf(o[e] * inv);
        ((unsigned short*)&w1)[e] = f2bf(o[4 + e] * inv);
        ((unsigned short*)&w2)[e] = f2bf(o[8 + e] * inv);
        ((unsigned short*)&w3)[e] = f2bf(o[12 + e] * inv);
    }
    unsigned short* dst = vals + ((size_t)(b * S_ + it * 64 + ii)) * E_ + h * 64 + c;
    *(ushort4*)(dst)      = w0;
    *(ushort4*)(dst + 4)  = w1;
    *(ushort4*)(dst + 8)  = w2;
    *(ushort4*)(dst + 12) = w3;
}

// ---------------------------------------------------------------------------
// Launcher. Workspace (shorts unless noted): xb 2359296; 7x589824 weights/rel;
// qb,kb,vtb 3x2359296; pkb,pqb 2x589824; valsb 2359296; part_O 6x576x4096;
// part_ml fp32 6x576x128. ~69 MiB.
// ---------------------------------------------------------------------------
extern "C" void kernel_launch(void* const* d_in, const int* in_sizes, int n_in,
                              void* d_out, int out_size, void* d_ws, size_t ws_size,
                              hipStream_t stream)
{
    const float* x         = (const float*)d_in[0];
    const int*   mask      = (const int*)d_in[1];
    const int*   seg       = (const int*)d_in[2];
    const float* sep       = (const float*)d_in[3];
    const float* Wq        = (const float*)d_in[4];
    const float* bq        = (const float*)d_in[5];
    const float* Wk        = (const float*)d_in[6];
    const float* bk        = (const float*)d_in[7];
    const float* Wv        = (const float*)d_in[8];
    const float* bv        = (const float*)d_in[9];
    const float* rel_emb   = (const float*)d_in[10];
    const float* Wpk       = (const float*)d_in[11];
    const float* bpk       = (const float*)d_in[12];
    const float* Wpq       = (const float*)d_in[13];
    const float* bpq       = (const float*)d_in[14];
    const float* same_bias = (const float*)d_in[15];
    const float* cross_bias= (const float*)d_in[16];
    const float* sep_scale = (const float*)d_in[17];
    const float* sep_decay = (const float*)d_in[18];
    const float* Wo        = (const float*)d_in[19];
    const float* bo        = (const float*)d_in[20];

    const size_t QKVN = (size_t)B_ * S_ * E_;   // 2359296
    const size_t WN   = (size_t)768 * 768;      //  589824

    unsigned short* xb    = (unsigned short*)d_ws;
    unsigned short* wqb   = xb   + QKVN;
    unsigned short* wkb   = wqb  + WN;
    unsigned short* wvb   = wkb  + WN;
    unsigned short* wob   = wvb  + WN;
    unsigned short* wpkb  = wob  + WN;
    unsigned short* wpqb  = wpkb + WN;
    unsigned short* relb  = wpqb + WN;
    unsigned short* qb    = relb + WN;
    unsigned short* kb    = qb   + QKVN;
    unsigned short* vtb   = kb   + QKVN;
    unsigned short* pkb   = vtb  + QKVN;
    unsigned short* pqb   = pkb  + WN;
    unsigned short* valsb = pqb  + WN;
    unsigned short* partO = valsb + QKVN;                       // 6*576*4096 shorts
    float*          partml= (float*)(partO + (size_t)6 * 576 * 4096);

    // 1) convert all operands to bf16
    convert_all<<<dim3(576, 11), 256, 0, stream>>>(
        x, Wq, Wk, Wv, Wo, Wpk, Wpq, rel_emb + (size_t)128 * D_,
        xb, wqb, wkb, wvb, wob, wpkb, wpqb, relb);

    // 2) fused Q/K/Vt/pk/pq projections (64x128 tiles, 1008 blocks)
    proj_all<<<dim3(1008), 256, 0, stream>>>(
        xb, relb, wqb, wkb, wvb, wpkb, wpqb,
        bq, bk, bv, bpk, bpq, qb, kb, vtb, pkb, pqb);

    // 3) MFMA flash attention (R15 proven version), split-j x6
    attn_mfma<<<dim3(6, 12, 48), 256, 0, stream>>>(
        qb, kb, vtb, pkb, pqb, seg, sep, mask,
        same_bias, cross_bias, sep_scale, sep_decay, partO, partml);

    // 4) merge partials -> valsb
    merge_attn<<<dim3(576), 256, 0, stream>>>(partO, partml, valsb);

    // 5) output projection (64x128 tiles, 288 blocks, direct stores)
    gemm_out<<<dim3(288), 256, 0, stream>>>(valsb, wob, bo, (float*)d_out);
}

// Round 14
// 199.835 us; speedup vs baseline: 1.2002x; 1.0082x over previous
//
#include <hip/hip_runtime.h>
#include <math.h>

// Problem constants
#define B_  8
#define S_  384
#define H_  12
#define HD_ 64
#define E_  768
#define D_  768

typedef float  floatx4 __attribute__((ext_vector_type(4)));
typedef __bf16 bf16x8  __attribute__((ext_vector_type(8)));
typedef unsigned int ux4 __attribute__((ext_vector_type(4)));

__device__ __forceinline__ unsigned short f2bf(float f) {
    union { float f; unsigned u; } x; x.f = f;
    unsigned r = x.u + 0x7fff + ((x.u >> 16) & 1);
    return (unsigned short)(r >> 16);
}
__device__ __forceinline__ float bf2f(unsigned short u) {
    union { unsigned u; float f; } x; x.u = ((unsigned)u) << 16;
    return x.f;
}
__device__ __forceinline__ bf16x8 gld8(const unsigned short* p) {
    return __builtin_bit_cast(bf16x8, *(const ux4*)p);
}
// swizzled chunk address (shorts) for 128B-row tiles staged via global_load_lds
__device__ __forceinline__ int tadr(int row, int cD) {
    return (row * 8 + (cD ^ (row & 7))) * 8;
}
__device__ __forceinline__ bf16x8 lds8(const unsigned short* base, int row, int cD) {
    return __builtin_bit_cast(bf16x8, *(const ux4*)(base + tadr(row, cD)));
}

// ---------------------------------------------------------------------------
// Fused fp32 -> bf16 convert. grid=(576,11).
// ---------------------------------------------------------------------------
__global__ __launch_bounds__(256) void convert_all(
    const float* __restrict__ x,
    const float* __restrict__ Wq, const float* __restrict__ Wk,
    const float* __restrict__ Wv, const float* __restrict__ Wo,
    const float* __restrict__ Wpk, const float* __restrict__ Wpq,
    const float* __restrict__ rel128,
    unsigned short* __restrict__ xb,
    unsigned short* __restrict__ wqb, unsigned short* __restrict__ wkb,
    unsigned short* __restrict__ wvb, unsigned short* __restrict__ wob,
    unsigned short* __restrict__ wpkb, unsigned short* __restrict__ wpqb,
    unsigned short* __restrict__ relb)
{
    const int seg = blockIdx.y;
    const int e = (blockIdx.x * 256 + threadIdx.x) * 4;
    const float* src;
    unsigned short* dst;
    if (seg < 4)       { src = x + (size_t)seg * 589824; dst = xb + (size_t)seg * 589824; }
    else if (seg == 4) { src = Wq;  dst = wqb; }
    else if (seg == 5) { src = Wk;  dst = wkb; }
    else if (seg == 6) { src = Wv;  dst = wvb; }
    else if (seg == 7) { src = Wo;  dst = wob; }
    else if (seg == 8) { src = Wpk; dst = wpkb; }
    else if (seg == 9) { src = Wpq; dst = wpqb; }
    else               { src = rel128; dst = relb; }

    float4 v;
    if (seg == 10 && e >= 767 * 768) v = make_float4(0.f, 0.f, 0.f, 0.f);
    else                             v = *(const float4*)(src + e);
    ushort4 o;
    o.x = f2bf(v.x); o.y = f2bf(v.y); o.z = f2bf(v.z); o.w = f2bf(v.w);
    *(ushort4*)(dst + e) = o;
}

// ---------------------------------------------------------------------------
// Projection GEMMs (Q,K,Vt,pk,pq), 64x128 tile, BK=64, flat grid of 1008.
// R23: XCD-aware swizzle (1008%8==0): work = (bid&7)*126 + (bid>>3), so each
// XCD's L2 serves 126 CONSECUTIVE work items (same A m-panel across 6 n-tiles)
// instead of round-robin scattering them over 8 XCDs.
//   work <  864 : z = work/288 (Q,K,Vt), 48 m-tiles x 6 n-tiles
//   work >= 864 : z = 3 + (work-864)/72 (pk,pq), 12 m-tiles x 6 n-tiles
// ---------------------------------------------------------------------------
__global__ __launch_bounds__(256) void proj_all(
    const unsigned short* __restrict__ xb, const unsigned short* __restrict__ relb,
    const unsigned short* __restrict__ wq, const unsigned short* __restrict__ wk,
    const unsigned short* __restrict__ wv, const unsigned short* __restrict__ wpk,
    const unsigned short* __restrict__ wpq,
    const float* __restrict__ bq, const float* __restrict__ bk,
    const float* __restrict__ bv, const float* __restrict__ bpk,
    const float* __restrict__ bpq,
    unsigned short* __restrict__ qb, unsigned short* __restrict__ kb,
    unsigned short* __restrict__ vtb, unsigned short* __restrict__ pkb,
    unsigned short* __restrict__ pqb)
{
    const int bid = (int)(blockIdx.x & 7) * 126 + (int)(blockIdx.x >> 3);
    int z, mt, nt;
    if (bid < 864) {
        z = bid / 288; const int r = bid - z * 288; mt = r / 6; nt = r - mt * 6;
    } else {
        const int r2 = bid - 864; z = 3 + r2 / 72;
        const int r = r2 % 72; mt = r / 6; nt = r - mt * 6;
    }
    const int m0 = mt * 64, n0 = nt * 128;

    const unsigned short* A = (z < 3) ? xb : relb;
    const unsigned short* W = (z == 0) ? wq : (z == 1) ? wk : (z == 2) ? wv
                            : (z == 3) ? wpk : wpq;
    const float* bias = (z == 0) ? bq : (z == 1) ? bk : (z == 2) ? bv
                      : (z == 3) ? bpk : bpq;
    unsigned short* C = (z == 0) ? qb : (z == 1) ? kb : (z == 2) ? vtb
                      : (z == 3) ? pkb : pqb;

    __shared__ unsigned short As[64 * 64];     //  8 KB
    __shared__ unsigned short Ws[128 * 64];    // 16 KB

    const int tid  = threadIdx.x;
    const int lane = tid & 63;
    const int wv_  = tid >> 6;                 // N-strip of 32
    const int quad = lane >> 4, l16 = lane & 15;

    floatx4 acc[4][2];
#pragma unroll
    for (int i = 0; i < 4; ++i)
#pragma unroll
        for (int j = 0; j < 2; ++j) acc[i][j] = (floatx4){0.f, 0.f, 0.f, 0.f};

    for (int k0 = 0; k0 < 768; k0 += 64) {
        __syncthreads();
#pragma unroll
        for (int r = 0; r < 2; ++r) {
            const int idx = tid + 256 * r;     // 0..511: A 64 rows x 8 chunks
            const int row = idx >> 3, cL = idx & 7, cD = cL ^ (row & 7);
            __builtin_amdgcn_global_load_lds(
                (__attribute__((address_space(1))) void*)(A + (size_t)(m0 + row) * 768 + k0 + cD * 8),
                (__attribute__((address_space(3))) void*)&As[idx * 8], 16, 0, 0);
        }
#pragma unroll
        for (int r = 0; r < 4; ++r) {
            const int idx = tid + 256 * r;     // 0..1023: W 128 rows x 8 chunks
            const int row = idx >> 3, cL = idx & 7, cD = cL ^ (row & 7);
            __builtin_amdgcn_global_load_lds(
                (__attribute__((address_space(1))) void*)(W + (size_t)(n0 + row) * 768 + k0 + cD * 8),
                (__attribute__((address_space(3))) void*)&Ws[idx * 8], 16, 0, 0);
        }
        __syncthreads();

        bf16x8 a[4][2], b[2][2];
#pragma unroll
        for (int mi = 0; mi < 4; ++mi)
#pragma unroll
            for (int kc = 0; kc < 2; ++kc)
                a[mi][kc] = lds8(As, mi * 16 + l16, kc * 4 + quad);
#pragma unroll
        for (int ni = 0; ni < 2; ++ni)
#pragma unroll
            for (int kc = 0; kc < 2; ++kc)
                b[ni][kc] = lds8(Ws, wv_ * 32 + ni * 16 + l16, kc * 4 + quad);
#pragma unroll
        for (int mi = 0; mi < 4; ++mi)
#pragma unroll
            for (int ni = 0; ni < 2; ++ni)
#pragma unroll
                for (int kc = 0; kc < 2; ++kc)
                    acc[mi][ni] = __builtin_amdgcn_mfma_f32_16x16x32_bf16(
                        a[mi][kc], b[ni][kc], acc[mi][ni], 0, 0, 0);
    }

#pragma unroll
    for (int ni = 0; ni < 2; ++ni) {
        const int n = n0 + wv_ * 32 + ni * 16 + l16;
        const float bn = bias[n];
#pragma unroll
        for (int mi = 0; mi < 4; ++mi) {
            const int mbase = m0 + mi * 16 + quad * 4;
            if (z == 2) {
                const int bb = mbase / S_, s = mbase - bb * S_;
                const int h = n >> 6, hd = n & 63;
                ushort4 o;
                o.x = f2bf(acc[mi][ni][0] + bn);
                o.y = f2bf(acc[mi][ni][1] + bn);
                o.z = f2bf(acc[mi][ni][2] + bn);
                o.w = f2bf(acc[mi][ni][3] + bn);
                *(ushort4*)&C[(((size_t)(bb * H_ + h) << 6) + hd) * S_ + s] = o;
            } else if (z < 2) {
#pragma unroll
                for (int reg = 0; reg < 4; ++reg) {
                    const int m = mbase + reg;
                    const int bb = m / S_, s = m - bb * S_;
                    const int h = n >> 6, hd = n & 63;
                    C[(((size_t)(bb * H_ + h) * S_ + s) << 6) + hd] =
                        f2bf(acc[mi][ni][reg] + bn);
                }
            } else {
#pragma unroll
                for (int reg = 0; reg < 4; ++reg)
                    C[(size_t)(mbase + reg) * 768 + n] = f2bf(acc[mi][ni][reg] + bn);
            }
        }
    }
}

// ---------------------------------------------------------------------------
// Output projection: 64x128 tile, BK=64, grid = 288 (48 m-tiles x 6 n-tiles).
// R23: XCD swizzle (288%8==0): work = (bid&7)*36 + (bid>>3).
// Direct fp32 stores (best-measured form).
// ---------------------------------------------------------------------------
__global__ __launch_bounds__(256) void gemm_out(
    const unsigned short* __restrict__ A, const unsigned short* __restrict__ W,
    const float* __restrict__ bias, float* __restrict__ C)
{
    const int bid = (int)(blockIdx.x & 7) * 36 + (int)(blockIdx.x >> 3);
    const int mt = bid / 6, nt = bid - mt * 6;
    const int m0 = mt * 64, n0 = nt * 128;

    __shared__ unsigned short As[64 * 64];
    __shared__ unsigned short Ws[128 * 64];

    const int tid  = threadIdx.x;
    const int lane = tid & 63;
    const int wv_  = tid >> 6;
    const int quad = lane >> 4, l16 = lane & 15;

    floatx4 acc[4][2];
#pragma unroll
    for (int i = 0; i < 4; ++i)
#pragma unroll
        for (int j = 0; j < 2; ++j) acc[i][j] = (floatx4){0.f, 0.f, 0.f, 0.f};

    for (int k0 = 0; k0 < 768; k0 += 64) {
        __syncthreads();
#pragma unroll
        for (int r = 0; r < 2; ++r) {
            const int idx = tid + 256 * r;
            const int row = idx >> 3, cL = idx & 7, cD = cL ^ (row & 7);
            __builtin_amdgcn_global_load_lds(
                (__attribute__((address_space(1))) void*)(A + (size_t)(m0 + row) * 768 + k0 + cD * 8),
                (__attribute__((address_space(3))) void*)&As[idx * 8], 16, 0, 0);
        }
#pragma unroll
        for (int r = 0; r < 4; ++r) {
            const int idx = tid + 256 * r;
            const int row = idx >> 3, cL = idx & 7, cD = cL ^ (row & 7);
            __builtin_amdgcn_global_load_lds(
                (__attribute__((address_space(1))) void*)(W + (size_t)(n0 + row) * 768 + k0 + cD * 8),
                (__attribute__((address_space(3))) void*)&Ws[idx * 8], 16, 0, 0);
        }
        __syncthreads();

        bf16x8 a[4][2], b[2][2];
#pragma unroll
        for (int mi = 0; mi < 4; ++mi)
#pragma unroll
            for (int kc = 0; kc < 2; ++kc)
                a[mi][kc] = lds8(As, mi * 16 + l16, kc * 4 + quad);
#pragma unroll
        for (int ni = 0; ni < 2; ++ni)
#pragma unroll
            for (int kc = 0; kc < 2; ++kc)
                b[ni][kc] = lds8(Ws, wv_ * 32 + ni * 16 + l16, kc * 4 + quad);
#pragma unroll
        for (int mi = 0; mi < 4; ++mi)
#pragma unroll
            for (int ni = 0; ni < 2; ++ni)
#pragma unroll
                for (int kc = 0; kc < 2; ++kc)
                    acc[mi][ni] = __builtin_amdgcn_mfma_f32_16x16x32_bf16(
                        a[mi][kc], b[ni][kc], acc[mi][ni], 0, 0, 0);
    }

#pragma unroll
    for (int ni = 0; ni < 2; ++ni) {
        const int n = n0 + wv_ * 32 + ni * 16 + l16;
        const float bn = bias[n];
#pragma unroll
        for (int mi = 0; mi < 4; ++mi)
#pragma unroll
            for (int reg = 0; reg < 4; ++reg) {
                const int m = m0 + mi * 16 + quad * 4 + reg;
                C[(size_t)m * 768 + n] = acc[mi][ni][reg] + bn;
            }
    }
}

// ---------------------------------------------------------------------------
// MFMA flash attention, R15 core + R23 XCD swizzle. Flat grid 3456 (%8==0):
// work = (bid&7)*432 + (bid>>3); decode it = work%6, h = (work/6)%12,
// b = work/432... (see below). Each XCD's L2 serves 432 CONSECUTIVE work
// items: groups of 6 it-blocks sharing the SAME K-tile, Vt-tile (same b,h,jt)
// and overlapping PK/PQ windows -- previously scattered over 8 XCDs.
// Kernel body is byte-identical to the proven R15 version (57.5-58.7 us;
// FETCH 36.4 MB, WRITE 42.5 MB, conflicts 884736, VGPR 84).
// ---------------------------------------------------------------------------
__global__ __launch_bounds__(256, 3) void attn_mfma(
    const unsigned short* __restrict__ qg, const unsigned short* __restrict__ kg,
    const unsigned short* __restrict__ vtg,
    const unsigned short* __restrict__ pkg, const unsigned short* __restrict__ pqg,
    const int* __restrict__ seg, const float* __restrict__ sep,
    const int* __restrict__ mask,
    const float* __restrict__ same_bias, const float* __restrict__ cross_bias,
    const float* __restrict__ sep_scale, const float* __restrict__ sep_decay,
    unsigned short* __restrict__ part_O, float* __restrict__ part_ml)
{
    __shared__ unsigned short PKs[128 * 64];   // 16 KB, swizzled chunks
    __shared__ unsigned short PQs[128 * 64];   // 16 KB
    __shared__ float CP[64 * 68];              // 17 KB score tile

    const int tid  = threadIdx.x;
    const int lane = tid & 63, w = tid >> 6;
    const int l16  = lane & 15, quad = lane >> 4;
    // XCD-aware flat-id swizzle: each XCD gets 432 consecutive work items
    const int work = (int)(blockIdx.x & 7) * 432 + (int)(blockIdx.x >> 3);
    const int it = work % 6;
    const int h  = (work / 6) % 12;
    const int bz = work / 72;                  // 0..47 = b*6 + jt
    const int b  = bz / 6, jt = bz - 6 * b;
    const int i0 = it * 64, j0 = jt * 64;
    const size_t bh = (size_t)(b * H_ + h);

    const unsigned short* kbase  = kg  + bh * S_ * 64;
    const unsigned short* vtbase = vtg + bh * 64 * S_;
    const int dbase = i0 - j0 + 320;           // pk/pq window base (0..640)

    // ---- stage PK + PQ (128 rows x 128B each) via global_load_lds DMA ----
#pragma unroll
    for (int r = 0; r < 4; ++r) {
        const int idx = tid + 256 * r;         // 0..1023: 128 rows x 8 chunks
        const int srow = idx >> 3, cL = idx & 7, cD = cL ^ (srow & 7);
        const size_t go = (size_t)(dbase + srow) * 768 + h * 64 + cD * 8;
        __builtin_amdgcn_global_load_lds(
            (__attribute__((address_space(1))) void*)(pkg + go),
            (__attribute__((address_space(3))) void*)&PKs[idx * 8], 16, 0, 0);
        __builtin_amdgcn_global_load_lds(
            (__attribute__((address_space(1))) void*)(pqg + go),
            (__attribute__((address_space(3))) void*)&PQs[idx * 8], 16, 0, 0);
    }

    // ---- direct loads (fly during staging): Q, K, Vt fragments ----
    bf16x8 qf[2];
#pragma unroll
    for (int ks = 0; ks < 2; ++ks)
        qf[ks] = gld8(qg + (bh * S_ + i0 + 16 * w + l16) * 64 + ks * 32 + quad * 8);

    bf16x8 kf[4][2];
#pragma unroll
    for (int nj = 0; nj < 4; ++nj)
#pragma unroll
        for (int ks = 0; ks < 2; ++ks)
            kf[nj][ks] = gld8(kbase + (size_t)(j0 + 16 * nj + l16) * 64
                              + ks * 32 + quad * 8);

    bf16x8 vtf[4][2];
#pragma unroll
    for (int nd = 0; nd < 4; ++nd)
#pragma unroll
        for (int ks = 0; ks < 2; ++ks)
            vtf[nd][ks] = gld8(vtbase + (size_t)(16 * nd + l16) * S_
                               + j0 + ks * 32 + quad * 8);

    // ---- metadata (also in flight) ----
    const int row = 16 * w + l16;              // softmax row this lane owns
    const float aii = fabsf(sep[b * S_ + i0 + row]);
    const int   sii = seg[b * S_ + i0 + row];
    const float* sepj = sep  + b * S_ + j0;
    const int*   segj = seg  + b * S_ + j0;
    const int*   mskj = mask + b * S_ + j0;
    float ajv[16]; int sjv[16], mkv[16];
    *(float4*)&ajv[0]  = *(const float4*)&sepj[quad * 8];
    *(float4*)&ajv[4]  = *(const float4*)&sepj[quad * 8 + 4];
    *(float4*)&ajv[8]  = *(const float4*)&sepj[32 + quad * 8];
    *(float4*)&ajv[12] = *(const float4*)&sepj[32 + quad * 8 + 4];
    *(int4*)&sjv[0]  = *(const int4*)&segj[quad * 8];
    *(int4*)&sjv[4]  = *(const int4*)&segj[quad * 8 + 4];
    *(int4*)&sjv[8]  = *(const int4*)&segj[32 + quad * 8];
    *(int4*)&sjv[12] = *(const int4*)&segj[32 + quad * 8 + 4];
    *(int4*)&mkv[0]  = *(const int4*)&mskj[quad * 8];
    *(int4*)&mkv[4]  = *(const int4*)&mskj[quad * 8 + 4];
    *(int4*)&mkv[8]  = *(const int4*)&mskj[32 + quad * 8];
    *(int4*)&mkv[12] = *(const int4*)&mskj[32 + quad * 8 + 4];

    const float sb  = same_bias[h];
    const float cb  = cross_bias[h];
    const float ssc = sep_scale[h];
    const float sd  = sep_decay[h];
    const float dec = fmaxf(sd, 0.f) + log1pf(__expf(-fabsf(sd))) + 1e-4f;
    const float isc = 0.07216878364870323f;    // 1/sqrt(64*3)

    // bias precompute (VALU work during staging flight)
    float biasv[16]; unsigned mkbits = 0;
#pragma unroll
    for (int e = 0; e < 16; ++e) {
        const float gap = fabsf(aii - fabsf(ajv[e]));
        biasv[e] = (sii == sjv[e]) ? sb : cb + __expf(-gap * dec) * ssc;
        mkbits |= (mkv[e] != 0 ? 1u : 0u) << e;
    }

    // ---- c2c (needs only qf,kf): runs BEFORE the barrier, covers staging ----
#pragma unroll
    for (int nj = 0; nj < 4; ++nj) {
        floatx4 acc = (floatx4){0.f, 0.f, 0.f, 0.f};
#pragma unroll
        for (int ks = 0; ks < 2; ++ks)
            acc = __builtin_amdgcn_mfma_f32_16x16x32_bf16(qf[ks], kf[nj][ks], acc, 0, 0, 0);
#pragma unroll
        for (int reg = 0; reg < 4; ++reg) {
            const int ii = 16 * w + quad * 4 + reg;
            CP[ii * 68 + 16 * nj + l16] = acc[reg];
        }
    }

    __syncthreads();   // the ONE barrier: PK/PQ staging complete

    // ---- c2p (rows strip w): frags nd = w..w+4, scatter jj = ii-ddloc+63 ----
#pragma unroll
    for (int f = 0; f < 5; ++f) {
        const int nd = w + f;
        floatx4 acc = (floatx4){0.f, 0.f, 0.f, 0.f};
#pragma unroll
        for (int ks = 0; ks < 2; ++ks) {
            bf16x8 bf = lds8(PKs, 16 * nd + l16, ks * 4 + quad);
            acc = __builtin_amdgcn_mfma_f32_16x16x32_bf16(qf[ks], bf, acc, 0, 0, 0);
        }
        const int ddloc = 16 * nd + l16;
#pragma unroll
        for (int reg = 0; reg < 4; ++reg) {
            const int ii = 16 * w + quad * 4 + reg;
            const int jj = ii - ddloc + 63;
            if (jj >= 0 && jj < 64)
                CP[ii * 68 + jj] += acc[reg];      // unique writer per cell
        }
    }

    // ---- p2c (rows strip w): A=PQ (m=ddloc), B=K (n=jj) ----
#pragma unroll
    for (int f = 0; f < 5; ++f) {
        const int nd = w + f;
        bf16x8 pqf[2];
#pragma unroll
        for (int ks = 0; ks < 2; ++ks)
            pqf[ks] = lds8(PQs, 16 * nd + l16, ks * 4 + quad);
#pragma unroll
        for (int g = 0; g < 2; ++g) {
            const int nj = (g == 0) ? (3 - f) : (4 - f);
            if (nj < 0 || nj > 3) continue;
            floatx4 acc = (floatx4){0.f, 0.f, 0.f, 0.f};
#pragma unroll
            for (int ks = 0; ks < 2; ++ks)
                acc = __builtin_amdgcn_mfma_f32_16x16x32_bf16(pqf[ks], kf[nj][ks], acc, 0, 0, 0);
            const int jj = 16 * nj + l16;
#pragma unroll
            for (int reg = 0; reg < 4; ++reg) {
                const int ddloc = 16 * nd + quad * 4 + reg;
                const int ii = ddloc + jj - 63;
                if (ii >= 16 * w && ii < 16 * w + 16)
                    CP[ii * 68 + jj] += acc[reg];  // unique writer per cell
            }
        }
    }

    // ---- register softmax: lane owns row `row`, its 16 PV-frag cols ----
    floatx4 cp0 = *(const floatx4*)&CP[row * 68 + quad * 8];
    floatx4 cp1 = *(const floatx4*)&CP[row * 68 + quad * 8 + 4];
    floatx4 cp2 = *(const floatx4*)&CP[row * 68 + 32 + quad * 8];
    floatx4 cp3 = *(const floatx4*)&CP[row * 68 + 32 + quad * 8 + 4];

    float lg[16];
    float tmax = -INFINITY;
#pragma unroll
    for (int e = 0; e < 16; ++e) {
        const float cpv = (e < 4) ? cp0[e] : (e < 8) ? cp1[e - 4]
                        : (e < 12) ? cp2[e - 8] : cp3[e - 12];
        float xv = cpv * isc + biasv[e];
        if (!((mkbits >> e) & 1u)) xv = -9.0e15f;
        lg[e] = xv;
        tmax = fmaxf(tmax, xv);
    }
    tmax = fmaxf(tmax, __shfl_xor(tmax, 16));
    tmax = fmaxf(tmax, __shfl_xor(tmax, 32));

    float rs = 0.f;
    unsigned int pk32[8];
#pragma unroll
    for (int e = 0; e < 8; ++e) {
        const float e0 = __expf(lg[2 * e]     - tmax);
        const float e1 = __expf(lg[2 * e + 1] - tmax);
        rs += e0 + e1;
        pk32[e] = (unsigned)f2bf(e0) | ((unsigned)f2bf(e1) << 16);
    }
    rs += __shfl_xor(rs, 16);
    rs += __shfl_xor(rs, 32);

    float* pml = part_ml + (size_t)(jt * 576 + ((b * H_ + h) * 6 + it)) * 128;
    if (quad == 0) {
        pml[row]      = tmax;
        pml[64 + row] = rs;
    }

    // ---- PV: O = P x Vt; pA straight from registers, vtf preloaded ----
    bf16x8 pA[2];
    pA[0] = __builtin_bit_cast(bf16x8, (ux4){pk32[0], pk32[1], pk32[2], pk32[3]});
    pA[1] = __builtin_bit_cast(bf16x8, (ux4){pk32[4], pk32[5], pk32[6], pk32[7]});
    floatx4 O[4];
#pragma unroll
    for (int nd = 0; nd < 4; ++nd) {
        O[nd] = (floatx4){0.f, 0.f, 0.f, 0.f};
#pragma unroll
        for (int ks = 0; ks < 2; ++ks)
            O[nd] = __builtin_amdgcn_mfma_f32_16x16x32_bf16(pA[ks], vtf[nd][ks], O[nd], 0, 0, 0);
    }

    // ---- epilogue: write unnormalized partial O ----
    unsigned short* pO = part_O + (size_t)(jt * 576 + ((b * H_ + h) * 6 + it)) * 4096;
#pragma unroll
    for (int nd = 0; nd < 4; ++nd) {
        const int d = 16 * nd + l16;
#pragma unroll
        for (int reg = 0; reg < 4; ++reg) {
            const int ii = 16 * w + quad * 4 + reg;
            pO[ii * 64 + d] = f2bf(O[nd][reg]);
        }
    }
}

// ---------------------------------------------------------------------------
// Merge the 6 split-j partials -> vals (bf16, (B,S,E)). grid=576, 256 thr.
// ---------------------------------------------------------------------------
__global__ __launch_bounds__(256) void merge_attn(
    const unsigned short* __restrict__ part_O, const float* __restrict__ part_ml,
    unsigned short* __restrict__ vals)
{
    const int idx = blockIdx.x;                 // ((b*H+h)*6+it)
    const int b  = idx / (H_ * 6);
    const int r  = idx - b * H_ * 6;
    const int h  = r / 6, it = r - h * 6;
    const int tid = threadIdx.x;
    const int ii = tid >> 2, c = (tid & 3) * 16;

    float m[6], l[6];
#pragma unroll
    for (int jc = 0; jc < 6; ++jc) {
        const float* pml = part_ml + (size_t)(jc * 576 + idx) * 128;
        m[jc] = pml[ii];
        l[jc] = pml[64 + ii];
    }
    float M = m[0];
#pragma unroll
    for (int jc = 1; jc < 6; ++jc) M = fmaxf(M, m[jc]);
    float wsum = 0.f, wc[6];
#pragma unroll
    for (int jc = 0; jc < 6; ++jc) {
        wc[jc] = __expf(m[jc] - M);
        wsum += wc[jc] * l[jc];
    }
    const float inv = (wsum > 0.f) ? 1.f / wsum : 0.f;

    float o[16];
#pragma unroll
    for (int e = 0; e < 16; ++e) o[e] = 0.f;
#pragma unroll
    for (int jc = 0; jc < 6; ++jc) {
        const unsigned short* pO = part_O + ((size_t)(jc * 576 + idx)) * 4096
                                 + ii * 64 + c;
        ux4 u0 = *(const ux4*)pO;
        ux4 u1 = *(const ux4*)(pO + 8);
        const unsigned short* us0 = (const unsigned short*)&u0;
        const unsigned short* us1 = (const unsigned short*)&u1;
#pragma unroll
        for (int e = 0; e < 8; ++e) {
            o[e]     += wc[jc] * bf2f(us0[e]);
            o[8 + e] += wc[jc] * bf2f(us1[e]);
        }
    }
    ushort4 w0, w1, w2, w3;
#pragma unroll
    for (int e = 0; e < 4; ++e) {
        ((unsigned short*)&w0)[e] = f2bf(o[e] * inv);
        ((unsigned short*)&w1)[e] = f2bf(o[4 + e] * inv);
        ((unsigned short*)&w2)[e] = f2bf(o[8 + e] * inv);
        ((unsigned short*)&w3)[e] = f2bf(o[12 + e] * inv);
    }
    unsigned short* dst = vals + ((size_t)(b * S_ + it * 64 + ii)) * E_ + h * 64 + c;
    *(ushort4*)(dst)      = w0;
    *(ushort4*)(dst + 4)  = w1;
    *(ushort4*)(dst + 8)  = w2;
    *(ushort4*)(dst + 12) = w3;
}

// ---------------------------------------------------------------------------
// Launcher. Workspace (shorts unless noted): xb 2359296; 7x589824 weights/rel;
// qb,kb,vtb 3x2359296; pkb,pqb 2x589824; valsb 2359296; part_O 6x576x4096;
// part_ml fp32 6x576x128. ~69 MiB.
// ---------------------------------------------------------------------------
extern "C" void kernel_launch(void* const* d_in, const int* in_sizes, int n_in,
                              void* d_out, int out_size, void* d_ws, size_t ws_size,
                              hipStream_t stream)
{
    const float* x         = (const float*)d_in[0];
    const int*   mask      = (const int*)d_in[1];
    const int*   seg       = (const int*)d_in[2];
    const float* sep       = (const float*)d_in[3];
    const float* Wq        = (const float*)d_in[4];
    const float* bq        = (const float*)d_in[5];
    const float* Wk        = (const float*)d_in[6];
    const float* bk        = (const float*)d_in[7];
    const float* Wv        = (const float*)d_in[8];
    const float* bv        = (const float*)d_in[9];
    const float* rel_emb   = (const float*)d_in[10];
    const float* Wpk       = (const float*)d_in[11];
    const float* bpk       = (const float*)d_in[12];
    const float* Wpq       = (const float*)d_in[13];
    const float* bpq       = (const float*)d_in[14];
    const float* same_bias = (const float*)d_in[15];
    const float* cross_bias= (const float*)d_in[16];
    const float* sep_scale = (const float*)d_in[17];
    const float* sep_decay = (const float*)d_in[18];
    const float* Wo        = (const float*)d_in[19];
    const float* bo        = (const float*)d_in[20];

    const size_t QKVN = (size_t)B_ * S_ * E_;   // 2359296
    const size_t WN   = (size_t)768 * 768;      //  589824

    unsigned short* xb    = (unsigned short*)d_ws;
    unsigned short* wqb   = xb   + QKVN;
    unsigned short* wkb   = wqb  + WN;
    unsigned short* wvb   = wkb  + WN;
    unsigned short* wob   = wvb  + WN;
    unsigned short* wpkb  = wob  + WN;
    unsigned short* wpqb  = wpkb + WN;
    unsigned short* relb  = wpqb + WN;
    unsigned short* qb    = relb + WN;
    unsigned short* kb    = qb   + QKVN;
    unsigned short* vtb   = kb   + QKVN;
    unsigned short* pkb   = vtb  + QKVN;
    unsigned short* pqb   = pkb  + WN;
    unsigned short* valsb = pqb  + WN;
    unsigned short* partO = valsb + QKVN;                       // 6*576*4096 shorts
    float*          partml= (float*)(partO + (size_t)6 * 576 * 4096);

    // 1) convert all operands to bf16
    convert_all<<<dim3(576, 11), 256, 0, stream>>>(
        x, Wq, Wk, Wv, Wo, Wpk, Wpq, rel_emb + (size_t)128 * D_,
        xb, wqb, wkb, wvb, wob, wpkb, wpqb, relb);

    // 2) fused Q/K/Vt/pk/pq projections (64x128 tiles, 1008 blocks, XCD swz)
    proj_all<<<dim3(1008), 256, 0, stream>>>(
        xb, relb, wqb, wkb, wvb, wpkb, wpqb,
        bq, bk, bv, bpk, bpq, qb, kb, vtb, pkb, pqb);

    // 3) MFMA flash attention (R15 core, flat grid 3456 with XCD swizzle)
    attn_mfma<<<dim3(3456), 256, 0, stream>>>(
        qb, kb, vtb, pkb, pqb, seg, sep, mask,
        same_bias, cross_bias, sep_scale, sep_decay, partO, partml);

    // 4) merge partials -> valsb
    merge_attn<<<dim3(576), 256, 0, stream>>>(partO, partml, valsb);

    // 5) output projection (64x128 tiles, 288 blocks, XCD swz, direct stores)
    gemm_out<<<dim3(288), 256, 0, stream>>>(valsb, wob, bo, (float*)d_out);
}